// Round 1
// 1815.246 us; speedup vs baseline: 1.0542x; 1.0542x over previous
//
#include <hip/hip_runtime.h>
#include <hip/hip_bf16.h>

// Informer forward, MI355X. Round 9: fattn rebuilt around wave-per-row selection.
//  - 1024-thread blocks (16 waves), __launch_bounds__(1024,8) -> target 2 blocks/CU (32 waves).
//  - No K staging in LDS: phase-1 MFMA B-frags load direct from global (L2-hot), waves own
//    disjoint 16-col chunks; removes 8 syncthreads + 9 KiB LDS per block.
//  - MODE 0: top-16 extraction fused with PV (max fixed at it==0), pw/pidx/dinv eliminated.
//  - MODE 1/2: wave-per-row softmax + PV, 64 lanes = 64 head dims.
//  LDS 47 KiB -> ~35 KiB. Round-8 counters: fattn<0> L=512 193 us, MfmaUtil 0.9,
//  VALUBusy 48, Occupancy 31.6 -> latency-bound serial top-k; this parallelizes it 4x
//  across waves and ~2.7x more resident waves.
// Retained from round 8: GEMM staging via global_load_lds (width=16), one-time weight
// transpose prologue, dtype sniffer, fused QKV (N=1536), mgemm64 for N=512.
// Round 8: passed, absmax 0.0117, 1913 us.
// B=16, LE=512, LD=256, D=512, H=8, dk=64, DFF=2048, NE=3, ND=2, TOPK=16.
// Encoder lengths: 512 -> conv(514)/pool -> 257 -> conv(259)/pool -> 130.

#define DM 512
#define DK 64

using bf16 = __hip_bfloat16;
typedef short s8v __attribute__((ext_vector_type(8)));
typedef float f4v __attribute__((ext_vector_type(4)));

__device__ inline float b2f(bf16 x) { return __bfloat162float(x); }
__device__ inline float u2f(unsigned short u) { return __uint_as_float((unsigned)u << 16); }

// flag f: 1 = raw inputs are bf16, 0 = raw inputs are fp32. idx in ELEMENTS.
__device__ inline float ldw(const void* p, unsigned i, int f) {
    return f ? b2f(((const bf16*)p)[i]) : ((const float*)p)[i];
}

// order-preserving float->u32 (monotonic)
__device__ inline unsigned f2ord(float s) {
    unsigned u = __float_as_uint(s);
    return u ^ ((unsigned)((int)u >> 31) | 0x80000000u);
}

// async global->LDS, 16 B per lane; lds dst must be wave-uniform (lane i lands at dst+16*i)
__device__ inline void gl_lds16(const short* g, short* l) {
    __builtin_amdgcn_global_load_lds(
        (const __attribute__((address_space(1))) unsigned int*)g,
        (__attribute__((address_space(3))) unsigned int*)l,
        16, 0, 0);
}

// ---------------- dtype sniffer ----------------
__global__ __launch_bounds__(256) void sniff_k(const unsigned* __restrict__ x, int nwords,
                                               int* __restrict__ flag) {
    __shared__ int red[4];
    const int t = threadIdx.x;
    int c = 0;
    for (int i = t; i < nwords; i += 256) c += ((x[i] & 0x7F80u) == 0x3F80u) ? 1 : 0;
    #pragma unroll
    for (int o = 32; o > 0; o >>= 1) c += __shfl_down(c, o);
    __syncthreads();
    if ((t & 63) == 0) red[t >> 6] = c;
    __syncthreads();
    if (t == 0) flag[0] = (red[0] + red[1] + red[2] + red[3] > nwords / 20) ? 1 : 0;
}

// ---------------- reductions (blockDim == 256) ----------------
__device__ inline float block_sum256(float v, float* red) {
    #pragma unroll
    for (int o = 32; o > 0; o >>= 1) v += __shfl_down(v, o);
    __syncthreads();
    if ((threadIdx.x & 63) == 0) red[threadIdx.x >> 6] = v;
    __syncthreads();
    return red[0] + red[1] + red[2] + red[3];
}

// ---------------- embedding ----------------
__global__ __launch_bounds__(256) void embed_k(
    const void* __restrict__ xv, const void* __restrict__ vw, const void* __restrict__ vb,
    const void* __restrict__ xm, const void* __restrict__ mw, const void* __restrict__ mb,
    bf16* __restrict__ Out, int rows, int Cv, int Cm, const int* __restrict__ flagp)
{
    const int f = *flagp;
    int i = blockIdx.x * 256 + threadIdx.x;
    if (i >= rows * DM) return;
    const int r = i >> 9, d = i & 511;
    float acc = ldw(vb, d, f) + ldw(mb, d, f);
    for (int c = 0; c < Cv; ++c) acc += ldw(xv, r * Cv + c, f) * ldw(vw, c * DM + d, f);
    for (int c = 0; c < Cm; ++c) acc += ldw(xm, r * Cm + c, f) * ldw(mw, c * DM + d, f);
    Out[i] = __float2bfloat16(acc);
}

// ---------------- weight transpose: raw [K][N] -> bf16 [N][K]; z batches sub-mats ----------------
__global__ __launch_bounds__(256) void transp_k(
    const void* __restrict__ W, unsigned off, unsigned zstride, bf16* __restrict__ out,
    int K, int N, const int* __restrict__ flagp)
{
    __shared__ float tile[32][33];
    const int f = *flagp;
    const unsigned zo = blockIdx.z * zstride;
    const int t = threadIdx.x;
    const int tx = t & 31, ty = t >> 5;               // 32 x 8
    const int n0 = blockIdx.x * 32, k0 = blockIdx.y * 32;
    #pragma unroll
    for (int i = 0; i < 4; ++i)
        tile[ty + 8 * i][tx] = ldw(W, off + zo + (unsigned)(k0 + ty + 8 * i) * N + n0 + tx, f);
    __syncthreads();
    #pragma unroll
    for (int i = 0; i < 4; ++i)
        out[(size_t)zo + (size_t)(n0 + ty + 8 * i) * K + k0 + tx] = __float2bfloat16(tile[tx][ty + 8 * i]);
}

// ---------------- MFMA GEMM 128x128 (256 thr): C = A[M,K]@Wt[N,K]^T + bias ----------------
// Staging via global_load_lds (16 B/lane), unpadded [row][32]-short LDS tiles.
template<bool G3, bool RELU>
__global__ __launch_bounds__(256) void mgemm_k(
    const short* __restrict__ A, const int* __restrict__ ridx,
    const short* __restrict__ Wt,
    const void* __restrict__ bias, unsigned boff0,
    bf16* __restrict__ C, int M, int N, int K, int lda, int ldc,
    const int* __restrict__ flagp)
{
    __shared__ short As[128 * 32];
    __shared__ short Ws[128 * 32];
    const int t = threadIdx.x;
    const int bm = blockIdx.y * 128, bn = blockIdx.x * 128;
    const int lane = t & 63, wave = t >> 6;
    const int mbase = (wave >> 1) * 64, nbase = (wave & 1) * 64;
    const int l15 = lane & 15, quad = lane >> 4;
    const int lrow = lane >> 2, lk = (lane & 3) * 8;

    f4v acc[4][4] = {};

    for (int k0 = 0; k0 < K; k0 += 32) {
        __syncthreads();
        #pragma unroll
        for (int j = 0; j < 2; ++j) {
            const int rb = wave * 32 + j * 16;
            const int row = bm + rb + lrow;
            const int rowc = row < M ? row : M - 1;
            const short* g;
            if (G3) {
                const int r = ridx[(k0 >> 9) * M + rowc];
                g = A + (size_t)r * lda + (k0 & 511) + lk;
            } else {
                g = A + (size_t)rowc * lda + k0 + lk;
            }
            gl_lds16(g, &As[rb * 32]);
        }
        #pragma unroll
        for (int j = 0; j < 2; ++j) {
            const int nb = wave * 32 + j * 16;
            gl_lds16(Wt + (size_t)(bn + nb + lrow) * K + k0 + lk, &Ws[nb * 32]);
        }
        __syncthreads();
        s8v af[4], bfv[4];
        #pragma unroll
        for (int i = 0; i < 4; ++i) {
            af[i]  = *(const s8v*)&As[(mbase + i * 16 + l15) * 32 + quad * 8];
            bfv[i] = *(const s8v*)&Ws[(nbase + i * 16 + l15) * 32 + quad * 8];
        }
        #pragma unroll
        for (int mi = 0; mi < 4; ++mi)
            #pragma unroll
            for (int ni = 0; ni < 4; ++ni)
                acc[mi][ni] = __builtin_amdgcn_mfma_f32_16x16x32_bf16(
                    af[mi], bfv[ni], acc[mi][ni], 0, 0, 0);
    }

    const int f = *flagp;
    float bv[4];
    #pragma unroll
    for (int ni = 0; ni < 4; ++ni)
        bv[ni] = ldw(bias, boff0 + (unsigned)(bn + nbase + ni * 16 + l15), f);

    #pragma unroll
    for (int mi = 0; mi < 4; ++mi) {
        #pragma unroll
        for (int r = 0; r < 4; ++r) {
            const int row = bm + mbase + mi * 16 + quad * 4 + r;
            if (row < M) {
                #pragma unroll
                for (int ni = 0; ni < 4; ++ni) {
                    float o = acc[mi][ni][r] + bv[ni];
                    if (RELU) o = fmaxf(o, 0.f);
                    C[(size_t)row * ldc + bn + nbase + ni * 16 + l15] = __float2bfloat16(o);
                }
            }
        }
    }
}

// ---------------- MFMA GEMM 128x64 (128 thr, 2 waves): for N=512-class GEMMs ----------------
template<bool G3, bool RELU>
__global__ __launch_bounds__(128) void mgemm64_k(
    const short* __restrict__ A, const int* __restrict__ ridx,
    const short* __restrict__ Wt,
    const void* __restrict__ bias, unsigned boff0,
    bf16* __restrict__ C, int M, int N, int K, int lda, int ldc,
    const int* __restrict__ flagp)
{
    __shared__ short As[128 * 32];
    __shared__ short Ws[64 * 32];
    const int t = threadIdx.x;
    const int bm = blockIdx.y * 128, bn = blockIdx.x * 64;
    const int lane = t & 63, wave = t >> 6;
    const int mbase = wave * 64;
    const int l15 = lane & 15, quad = lane >> 4;
    const int lrow = lane >> 2, lk = (lane & 3) * 8;

    f4v acc[4][4] = {};

    for (int k0 = 0; k0 < K; k0 += 32) {
        __syncthreads();
        #pragma unroll
        for (int j = 0; j < 4; ++j) {
            const int rb = wave * 64 + j * 16;
            const int row = bm + rb + lrow;
            const int rowc = row < M ? row : M - 1;
            const short* g;
            if (G3) {
                const int r = ridx[(k0 >> 9) * M + rowc];
                g = A + (size_t)r * lda + (k0 & 511) + lk;
            } else {
                g = A + (size_t)rowc * lda + k0 + lk;
            }
            gl_lds16(g, &As[rb * 32]);
        }
        #pragma unroll
        for (int j = 0; j < 2; ++j) {
            const int nb = wave * 32 + j * 16;
            gl_lds16(Wt + (size_t)(bn + nb + lrow) * K + k0 + lk, &Ws[nb * 32]);
        }
        __syncthreads();
        s8v af[4], bfv[4];
        #pragma unroll
        for (int i = 0; i < 4; ++i) {
            af[i]  = *(const s8v*)&As[(mbase + i * 16 + l15) * 32 + quad * 8];
            bfv[i] = *(const s8v*)&Ws[(i * 16 + l15) * 32 + quad * 8];
        }
        #pragma unroll
        for (int mi = 0; mi < 4; ++mi)
            #pragma unroll
            for (int ni = 0; ni < 4; ++ni)
                acc[mi][ni] = __builtin_amdgcn_mfma_f32_16x16x32_bf16(
                    af[mi], bfv[ni], acc[mi][ni], 0, 0, 0);
    }

    const int f = *flagp;
    float bv[4];
    #pragma unroll
    for (int ni = 0; ni < 4; ++ni)
        bv[ni] = ldw(bias, boff0 + (unsigned)(bn + ni * 16 + l15), f);

    #pragma unroll
    for (int mi = 0; mi < 4; ++mi) {
        #pragma unroll
        for (int r = 0; r < 4; ++r) {
            const int row = bm + mbase + mi * 16 + quad * 4 + r;
            if (row < M) {
                #pragma unroll
                for (int ni = 0; ni < 4; ++ni) {
                    float o = acc[mi][ni][r] + bv[ni];
                    if (RELU) o = fmaxf(o, 0.f);
                    C[(size_t)row * ldc + bn + ni * 16 + l15] = __float2bfloat16(o);
                }
            }
        }
    }
}

// ---------------- fused tile attention (strided q/k/v), 1024 threads ----------------
// MODE 0: ProbSparse top-16. MODE 1: causal. MODE 2: plain cross.
// 16 waves: phase 1 = MFMA QK^T with direct-global K frags (disjoint 16-col chunks/wave);
// phase 2+3 = one wave per query row (lane = head dim). MODE 0 fuses selection with PV.
template<int MODE>
__global__ __launch_bounds__(1024, 8) void fattn_k(
    bf16* __restrict__ q, const bf16* __restrict__ k, const bf16* __restrict__ v,
    int ldq, int ldkv, int Lq, int Lk)
{
    __shared__ short Qs[16 * 72];
    __shared__ float S[16 * 516];

    const int t = threadIdx.x;
    const int q0 = blockIdx.x * 16, h = blockIdx.y, b = blockIdx.z;
    const int lane = t & 63, wave = t >> 6;
    const int l15 = lane & 15, quad = lane >> 4;

    const int qv = (Lq - q0) < 16 ? (Lq - q0) : 16;

    const bf16* Kbase = k + (size_t)b * Lk * ldkv + h * DK;
    const bf16* Vbase = v + (size_t)b * Lk * ldkv + h * DK;
    bf16* Qbase = q + (size_t)(b * Lq + q0) * ldq + h * DK;

    const int kmax = (MODE == 1) ? (q0 + 16 < Lk ? q0 + 16 : Lk) : Lk;
    const int ntile = (kmax + 63) >> 6;
    const int kpad = ntile << 6;
    const int nchunk = kpad >> 4;

    if (t < 128) {
        const int qr = t >> 3;
        const int qsrc = qr < qv ? qr : qv - 1;
        *(s8v*)&Qs[qr * 72 + (t & 7) * 8] =
            *(const s8v*)(Qbase + (size_t)qsrc * ldq + (t & 7) * 8);
    }
    __syncthreads();

    // ---- phase 1: S = QK^T / 8 (+ masks). wave w owns col chunks c = w, w+16, ... ----
    {
        const s8v a0 = *(const s8v*)&Qs[l15 * 72 + quad * 8];
        const s8v a1 = *(const s8v*)&Qs[l15 * 72 + 32 + quad * 8];
        for (int c = wave; c < nchunk; c += 16) {
            int srow = c * 16 + l15; if (srow >= Lk) srow = Lk - 1;
            const bf16* kp = Kbase + (size_t)srow * ldkv + quad * 8;
            const s8v b0 = *(const s8v*)kp;
            const s8v b1 = *(const s8v*)(kp + 32);
            f4v acc = {0.f, 0.f, 0.f, 0.f};
            acc = __builtin_amdgcn_mfma_f32_16x16x32_bf16(a0, b0, acc, 0, 0, 0);
            acc = __builtin_amdgcn_mfma_f32_16x16x32_bf16(a1, b1, acc, 0, 0, 0);
            const int colg = c * 16 + l15;
            #pragma unroll
            for (int r = 0; r < 4; ++r) {
                const int qrow = quad * 4 + r;
                float s = acc[r] * 0.125f;
                if (colg >= Lk) s = -1e9f;
                if (MODE == 1 && colg > q0 + qrow) s = -1e9f;
                S[qrow * 516 + colg] = s;
            }
        }
    }
    __syncthreads();

    // ---- phase 2+3 fused: one wave per query row; lane = output dim ----
    const int row = wave;
    float a = 0.f;
    float inv;
    if (MODE == 0) {
        unsigned key[8];
        #pragma unroll
        for (int j = 0; j < 8; ++j) {
            const int col = lane + 64 * j;
            key[j] = (col < kpad)
                ? ((f2ord(S[row * 516 + col]) & 0xFFFFFE00u) | (unsigned)col)
                : 0u;
        }
        float mr = 0.f, den = 0.f;
        for (int it = 0; it < 16; ++it) {
            unsigned mx = key[0];
            #pragma unroll
            for (int j = 1; j < 8; ++j) mx = mx > key[j] ? mx : key[j];
            #pragma unroll
            for (int off = 1; off < 64; off <<= 1) {
                const unsigned o = __shfl_xor(mx, off);
                mx = mx > o ? mx : o;
            }
            #pragma unroll
            for (int j = 0; j < 8; ++j) if (key[j] == mx) key[j] = 0u;
            const int col = (int)(mx & 511u);
            const float sval = S[row * 516 + col];   // uniform addr -> LDS broadcast
            if (it == 0) mr = sval;                  // top-1 == row max, fixed
            const float e = expf(sval - mr);
            den += e;
            a += e * b2f(Vbase[(size_t)col * ldkv + lane]);
        }
        inv = 1.f / den;
    } else {
        float lv = -INFINITY;
        #pragma unroll
        for (int j = 0; j < 8; ++j) {
            const int col = lane + 64 * j;
            if (col < kpad) lv = fmaxf(lv, S[row * 516 + col]);
        }
        #pragma unroll
        for (int off = 1; off < 64; off <<= 1) lv = fmaxf(lv, __shfl_xor(lv, off));
        float part = 0.f;
        #pragma unroll
        for (int j = 0; j < 8; ++j) {
            const int col = lane + 64 * j;
            if (col < kpad) {
                const float w = expf(S[row * 516 + col] - lv);
                S[row * 516 + col] = w;
                part += w;
            }
        }
        #pragma unroll
        for (int off = 1; off < 64; off <<= 1) part += __shfl_xor(part, off);
        inv = 1.f / part;
        const int kend = (MODE == 1) ? (q0 + row + 1 < kmax ? q0 + row + 1 : kmax) : kmax;
        for (int k2 = 0; k2 < kend; ++k2)
            a += S[row * 516 + k2] * b2f(Vbase[(size_t)k2 * ldkv + lane]);
    }
    if (row < qv)
        Qbase[(size_t)row * ldq + lane] = __float2bfloat16(a * inv);
}

// ---------------- layernorm over D=512, optional residual; in-place safe ----------------
__global__ __launch_bounds__(256) void ln_off_k(
    const bf16* __restrict__ X, const bf16* __restrict__ R,
    const void* __restrict__ gb, unsigned goff,
    bf16* __restrict__ Out, const int* __restrict__ flagp)
{
    __shared__ float red[4];
    const int f = *flagp;
    const int t = threadIdx.x;
    const size_t base = (size_t)blockIdx.x * DM;
    float v0 = b2f(X[base + t]), v1 = b2f(X[base + t + 256]);
    if (R) { v0 += b2f(R[base + t]); v1 += b2f(R[base + t + 256]); }
    const float mean = block_sum256(v0 + v1, red) * (1.f / 512.f);
    const float d0 = v0 - mean, d1 = v1 - mean;
    const float var = block_sum256(d0 * d0 + d1 * d1, red) * (1.f / 512.f);
    const float rstd = rsqrtf(var + 1e-5f);
    Out[base + t]       = __float2bfloat16(d0 * rstd * ldw(gb, goff + t, f)       + ldw(gb, goff + 512 + t, f));
    Out[base + t + 256] = __float2bfloat16(d1 * rstd * ldw(gb, goff + t + 256, f) + ldw(gb, goff + 768 + t, f));
}

// ---------------- conv distill helpers ----------------
// conv weights w[2][o][c][j] -> transposed GEMM layout wt[layer][o][j*512+c]
__global__ __launch_bounds__(256) void convw_k(const void* __restrict__ w,
                                               bf16* __restrict__ wt, int total,
                                               const int* __restrict__ flagp) {
    const int f = *flagp;
    int i = blockIdx.x * 256 + threadIdx.x;
    if (i >= total) return;
    const int layer = i / 786432, rem2 = i % 786432;
    const int o = rem2 / 1536, rem = rem2 % 1536;
    const int j = rem >> 9, c = rem & 511;
    wt[i] = __float2bfloat16(ldw(w, (unsigned)layer * 786432u + (unsigned)(o * 512 + c) * 3 + j, f));
}

__global__ __launch_bounds__(256) void convidx_k(int* __restrict__ idx, int Lc, int L, int total) {
    int i = blockIdx.x * 256 + threadIdx.x;
    if (i >= total) return;
    const int j = i / (16 * Lc), mrem = i % (16 * Lc);
    const int b = mrem / Lc, l = mrem % Lc;
    int src = l + j - 2;
    src %= L; if (src < 0) src += L;
    idx[i] = b * L + src;
}

__global__ __launch_bounds__(256) void bnstat1_k(const bf16* __restrict__ Y, float* __restrict__ part, int M) {
    const int t = threadIdx.x;
    float s0 = 0.f, q0 = 0.f, s1 = 0.f, q1 = 0.f;
    for (int r = blockIdx.x; r < M; r += gridDim.x) {
        const ushort2 u = *reinterpret_cast<const ushort2*>(Y + (size_t)r * DM + t * 2);
        const float a = u2f(u.x), c = u2f(u.y);
        s0 += a; q0 += a * a;
        s1 += c; q1 += c * c;
    }
    float* p = part + (size_t)blockIdx.x * 1024;
    p[2 * t] = s0; p[2 * t + 1] = s1;
    p[512 + 2 * t] = q0; p[512 + 2 * t + 1] = q1;
}

__global__ __launch_bounds__(256) void bnstat2_k(const float* __restrict__ part, float* __restrict__ stats,
                                                 int nchunk, int M) {
    const int ch = blockIdx.x * 256 + threadIdx.x;
    if (ch >= 512) return;
    float S = 0.f, Qs = 0.f;
    for (int c = 0; c < nchunk; ++c) { S += part[c * 1024 + ch]; Qs += part[c * 1024 + 512 + ch]; }
    const float mean = S / (float)M;
    const float var = Qs / (float)M - mean * mean;
    stats[ch] = mean;
    stats[512 + ch] = fmaxf(var, 0.f);
}

__global__ __launch_bounds__(256) void bnpool_k(
    const bf16* __restrict__ Yc, const float* __restrict__ stats,
    const void* __restrict__ g, const void* __restrict__ bb, unsigned off,
    bf16* __restrict__ Out, int Lc, int Lout, int total, const int* __restrict__ flagp)
{
    const int f = *flagp;
    int i = blockIdx.x * 256 + threadIdx.x;
    if (i >= total) return;
    const int ch = i & 511;
    const int lp = (i >> 9) % Lout;
    const int b = i / (512 * Lout);
    const float mean = stats[ch], var = stats[512 + ch];
    const float sc = ldw(g, off + ch, f) * rsqrtf(var + 1e-5f);
    const float sh = ldw(bb, off + ch, f) - mean * sc;
    float mx = -INFINITY;
    const int l0 = 2 * lp - 1;
    #pragma unroll
    for (int d = 0; d < 3; ++d) {
        const int l = l0 + d;
        if (l >= 0 && l < Lc) {
            float v = b2f(Yc[((size_t)b * Lc + l) * DM + ch]) * sc + sh;
            v = v > 0.f ? v : expm1f(v);  // ELU
            mx = fmaxf(mx, v);
        }
    }
    Out[((size_t)b * Lout + lp) * DM + ch] = __float2bfloat16(mx);
}

// ---------------- final projection to CO=7, dtype-matched store ----------------
__global__ __launch_bounds__(256) void fc_k(
    const bf16* __restrict__ Yn, const void* __restrict__ fcw, const void* __restrict__ fcb,
    void* __restrict__ out, int total, const int* __restrict__ flagp)
{
    const int f = *flagp;
    int i = blockIdx.x * 256 + threadIdx.x;
    if (i >= total) return;
    const int r = i / 7, co = i % 7;
    const bf16* yr = Yn + (size_t)r * DM;
    float acc = ldw(fcb, co, f);
    for (int d = 0; d < DM; ++d) acc += b2f(yr[d]) * ldw(fcw, d * 7 + co, f);
    if (f) ((bf16*)out)[i] = __float2bfloat16(acc);
    else   ((float*)out)[i] = acc;
}

// =============================================================================
extern "C" void kernel_launch(void* const* d_in, const int* in_sizes, int n_in,
                              void* d_out, int out_size, void* d_ws, size_t ws_size,
                              hipStream_t stream)
{
    const void* x_enc      = d_in[0];
    const void* x_mark_enc = d_in[1];
    const void* x_dec      = d_in[2];
    const void* x_mark_dec = d_in[3];
    const void* enc_vw = d_in[4];
    const void* enc_vb = d_in[5];
    const void* enc_mw = d_in[6];
    const void* enc_mb = d_in[7];
    const void* dec_vw = d_in[8];
    const void* dec_vb = d_in[9];
    const void* dec_mw = d_in[10];
    const void* dec_mb = d_in[11];
    const void* eW    = d_in[12];
    const void* ebi   = d_in[13];
    const void* effw1 = d_in[14];
    const void* effb1 = d_in[15];
    const void* effw2 = d_in[16];
    const void* effb2 = d_in[17];
    const void* eln1  = d_in[18];
    const void* eln2  = d_in[19];
    const void* cw    = d_in[20];
    const void* cb    = d_in[21];
    const void* cbn_g = d_in[22];
    const void* cbn_b = d_in[23];
    const void* enc_norm = d_in[24];
    const void* dsW   = d_in[25];
    const void* dsb   = d_in[26];
    const void* dcW   = d_in[27];
    const void* dcb   = d_in[28];
    const void* dffw1 = d_in[29];
    const void* dffb1 = d_in[30];
    const void* dffw2 = d_in[31];
    const void* dffb2 = d_in[32];
    const void* dln   = d_in[33];
    const void* dec_norm = d_in[34];
    const void* fcw   = d_in[35];
    const void* fcb   = d_in[36];

    // ---- workspace layout (~90 MiB; 111 MiB footprint ran clean in round 1) ----
    // X    [0, 8M)      : encoder acts; MEM + Yd in decoder phase
    // QKV  [8M, 40M)    : fused QKV / FFN hidden (aliased) / conv out / cross CQ+CKV
    // OUT  [40M, 48M)   : O-proj / FFN2 dest
    // WT   [48M, ~86.8M): ALL transposed weights (one-time prologue)
    // misc [88M, ~90M)  : IDX0/IDX1, PART, STATS, FLAG
    char* wsp = (char*)d_ws;
    bf16* X    = (bf16*)wsp;
    bf16* QKV  = (bf16*)(wsp + ((size_t)8 << 20));
    bf16* HID  = QKV;                                 // FFN hidden aliases dead QKV
    bf16* OUT  = (bf16*)(wsp + ((size_t)40 << 20));
    bf16* WT   = (bf16*)(wsp + ((size_t)48 << 20));
    int*   IDX0 = (int*)(wsp + ((size_t)88 << 20));   // 3*16*514 = 24672 ints
    int*   IDX1 = IDX0 + 24672;                       // 3*16*259 = 12432 ints
    float* PART = (float*)(wsp + ((size_t)89 << 20));
    float* STATS= (float*)(wsp + ((size_t)89 << 20) + (1 << 18));
    int*   FLAG = (int*)(wsp + ((size_t)89 << 20) + (1 << 18) + 4096);
    bf16* MEMb = X;                                               // [2080][512]
    bf16* Yd   = (bf16*)(wsp + (size_t)16 * 130 * 512 * 2);       // [4096][512]

    // transposed weight sub-arenas (element offsets)
    bf16* WTE  = WT;                    // enc QKVO: (i*4+q)*262144
    bf16* EW1T = WT + 3145728;          // + i*1048576
    bf16* EW2T = WT + 6291456;          // + i*1048576
    bf16* CWT  = WT + 9437184;          // + i*786432
    bf16* DSWt = WT + 11010048;         // + (i*4+q)*262144
    bf16* DCWt = WT + 13107200;
    bf16* DW1T = WT + 15204352;
    bf16* DW2T = WT + 17301504;

    auto cdiv = [](int a, int b) { return (a + b - 1) / b; };
    auto gemm = [&](const bf16* A, const bf16* Wt, const void* bias, unsigned boff,
                    bf16* C, int M, int N, int K, int lda, int ldc, bool relu) {
        dim3 g(N / 128, cdiv(M, 128));
        if (relu) mgemm_k<false, true><<<g, 256, 0, stream>>>(
            (const short*)A, nullptr, (const short*)Wt, bias, boff, C, M, N, K, lda, ldc, FLAG);
        else      mgemm_k<false, false><<<g, 256, 0, stream>>>(
            (const short*)A, nullptr, (const short*)Wt, bias, boff, C, M, N, K, lda, ldc, FLAG);
    };
    auto gemm64 = [&](const bf16* A, const bf16* Wt, const void* bias, unsigned boff,
                      bf16* C, int M, int N, int K, int lda, int ldc) {
        dim3 g(N / 64, cdiv(M, 128));
        mgemm64_k<false, false><<<g, 128, 0, stream>>>(
            (const short*)A, nullptr, (const short*)Wt, bias, boff, C, M, N, K, lda, ldc, FLAG);
    };
    auto transp = [&](const void* W, unsigned zstride, int nz, bf16* out, int K, int N) {
        transp_k<<<dim3(N / 32, K / 32, nz), 256, 0, stream>>>(W, 0u, zstride, out, K, N, FLAG);
    };

    // ---- prologue: sniff, all weight transposes, conv indices, embeddings ----
    sniff_k<<<1, 256, 0, stream>>>((const unsigned*)x_mark_enc, 16384, FLAG);
    transp(eW,    262144u, 12, WTE,  512, 512);
    transp(effw1, 1048576u, 3, EW1T, 512, 2048);
    transp(effw2, 1048576u, 3, EW2T, 2048, 512);
    convw_k<<<cdiv(1572864, 256), 256, 0, stream>>>(cw, CWT, 1572864, FLAG);
    transp(dsW,   262144u, 8, DSWt, 512, 512);
    transp(dcW,   262144u, 8, DCWt, 512, 512);
    transp(dffw1, 1048576u, 2, DW1T, 512, 2048);
    transp(dffw2, 1048576u, 2, DW2T, 2048, 512);
    convidx_k<<<cdiv(24672, 256), 256, 0, stream>>>(IDX0, 514, 512, 24672);
    convidx_k<<<cdiv(12432, 256), 256, 0, stream>>>(IDX1, 259, 257, 12432);
    embed_k<<<cdiv(16 * 512 * 512, 256), 256, 0, stream>>>(
        x_enc, enc_vw, enc_vb, x_mark_enc, enc_mw, enc_mb, X, 16 * 512, 7, 4, FLAG);

    // ---- encoder ----
    int L = 512;
    for (int i = 0; i < 3; ++i) {
        const int rows = 16 * L;
        const unsigned b0 = (unsigned)i * 4u * 512u;
        gemm(X, WTE + (size_t)i * 4 * 262144, ebi, b0, QKV, rows, 1536, 512, 512, 1536, false);
        fattn_k<0><<<dim3(cdiv(L, 16), 8, 16), 1024, 0, stream>>>(
            QKV, QKV + 512, QKV + 1024, 1536, 1536, L, L);
        gemm64(QKV, WTE + (size_t)(i * 4 + 3) * 262144, ebi, b0 + 1536u, OUT, rows, 512, 512, 1536, 512);
        ln_off_k<<<rows, 256, 0, stream>>>(X, OUT, eln1, (unsigned)i * 1024u, X, FLAG);

        gemm(X, EW1T + (size_t)i * 1048576, effb1, (unsigned)i * 2048u, HID, rows, 2048, 512, 512, 2048, true);
        gemm64(HID, EW2T + (size_t)i * 1048576, effb2, (unsigned)i * 512u, OUT, rows, 512, 2048, 2048, 512);
        ln_off_k<<<rows, 256, 0, stream>>>(X, OUT, eln2, (unsigned)i * 1024u, X, FLAG);

        if (i < 2) {
            const int Lc = L + 2, Mc = 16 * Lc;
            const int* IDXi = (i == 0) ? IDX0 : IDX1;
            mgemm64_k<true, false><<<dim3(8, cdiv(Mc, 128)), 128, 0, stream>>>(
                (const short*)X, IDXi, (const short*)(CWT + (size_t)i * 786432),
                cb, (unsigned)i * 512u, QKV, Mc, 512, 1536, 512, 512, FLAG);
            bnstat1_k<<<32, 256, 0, stream>>>(QKV, PART, Mc);
            bnstat2_k<<<2, 256, 0, stream>>>(PART, STATS, 32, Mc);
            const int Lout = (L + 1) / 2 + 1;   // 514->257, 259->130
            const int tot = 16 * Lout * 512;
            bnpool_k<<<cdiv(tot, 256), 256, 0, stream>>>(
                QKV, STATS, cbn_g, cbn_b, (unsigned)i * 512u, X, Lc, Lout, tot, FLAG);
            L = Lout;
        }
    }
    const int Lm = L;  // 130
    ln_off_k<<<16 * Lm, 256, 0, stream>>>(X, nullptr, enc_norm, 0u, MEMb, FLAG);

    // ---- decoder embedding ----
    const int rowsD = 16 * 256;
    embed_k<<<cdiv(rowsD * 512, 256), 256, 0, stream>>>(
        x_dec, dec_vw, dec_vb, x_mark_dec, dec_mw, dec_mb, Yd, rowsD, 7, 4, FLAG);

    // ---- decoder ----
    bf16* CQ  = QKV;                       // [4096][512]
    bf16* CKV = QKV + (size_t)4096 * 512;  // [2080][1024]
    for (int i = 0; i < 2; ++i) {
        const unsigned b0 = (unsigned)i * 4u * 512u;
        // self-attention
        gemm(Yd, DSWt + (size_t)i * 4 * 262144, dsb, b0, QKV, rowsD, 1536, 512, 512, 1536, false);
        fattn_k<1><<<dim3(16, 8, 16), 1024, 0, stream>>>(
            QKV, QKV + 512, QKV + 1024, 1536, 1536, 256, 256);
        gemm64(QKV, DSWt + (size_t)(i * 4 + 3) * 262144, dsb, b0 + 1536u, OUT, rowsD, 512, 512, 1536, 512);
        ln_off_k<<<rowsD, 256, 0, stream>>>(Yd, OUT, dln, (unsigned)(i * 3 + 0) * 1024u, Yd, FLAG);

        // cross-attention
        gemm64(Yd, DCWt + (size_t)i * 4 * 262144, dcb, b0, CQ, rowsD, 512, 512, 512, 512);
        gemm(MEMb, DCWt + (size_t)(i * 4 + 1) * 262144, dcb, b0 + 512u, CKV, 16 * Lm, 1024, 512, 512, 1024, false);
        fattn_k<2><<<dim3(16, 8, 16), 1024, 0, stream>>>(
            CQ, CKV, CKV + 512, 512, 1024, 256, Lm);
        gemm64(CQ, DCWt + (size_t)(i * 4 + 3) * 262144, dcb, b0 + 1536u, OUT, rowsD, 512, 512, 512, 512);
        ln_off_k<<<rowsD, 256, 0, stream>>>(Yd, OUT, dln, (unsigned)(i * 3 + 1) * 1024u, Yd, FLAG);

        // FFN
        gemm(Yd, DW1T + (size_t)i * 1048576, dffb1, (unsigned)i * 2048u, HID, rowsD, 2048, 512, 512, 2048, true);
        gemm64(HID, DW2T + (size_t)i * 1048576, dffb2, (unsigned)i * 512u, OUT, rowsD, 512, 2048, 2048, 512);
        ln_off_k<<<rowsD, 256, 0, stream>>>(Yd, OUT, dln, (unsigned)(i * 3 + 2) * 1024u, Yd, FLAG);
    }

    ln_off_k<<<rowsD, 256, 0, stream>>>(Yd, nullptr, dec_norm, 0u, OUT, FLAG);
    fc_k<<<cdiv(rowsD * 7, 256), 256, 0, stream>>>(OUT, fcw, fcb, d_out, rowsD * 7, FLAG);
}

// Round 3
// 1775.876 us; speedup vs baseline: 1.0776x; 1.0222x over previous
//
#include <hip/hip_runtime.h>
#include <hip/hip_bf16.h>

// Informer forward, MI355X. Round 11: fix round-10's padding bug in ballot radix-select.
//  - Round-10 FAILURE root cause: key build dropped the (col < kpad) guard. Valid only
//    for L=512; encoder layers 2/3 (L=257 kpad=320, L=130 kpad=192) read uninitialized
//    S LDS for cols >= kpad -> garbage in top-16 -> absmax 0.070.
//  - Fix: restore guard (key=0 for col >= kpad, ranks below all real keys).
//  - Also: binary search now runs over the FULL 32-bit key (qscore|col). Keys are
//    distinct -> search exits with count(key>=T)==16 exactly; single-class ballot
//    compaction reproduces round 9's top-16 set identically (no tie-order deviation).
//  - Selection cost ~270 cmp/popc (scalar-pipe counting) vs round 9's ~900 VALU +
//    96 shuffles + serialized V loads; PV issues 16 independent V loads.
// Retained: 1024-thr fattn (16 waves, wave-per-row), direct-global K frags,
// GEMM staging via global_load_lds (width=16), one-time weight transpose prologue,
// dtype sniffer, fused QKV (N=1536), mgemm64 for N=512.
// Round 9: passed, absmax 0.009, 1815 us (fattn<0> 123.7 us, VALUBusy 82% @ occ 79%).
// B=16, LE=512, LD=256, D=512, H=8, dk=64, DFF=2048, NE=3, ND=2, TOPK=16.
// Encoder lengths: 512 -> conv(514)/pool -> 257 -> conv(259)/pool -> 130.

#define DM 512
#define DK 64

using bf16 = __hip_bfloat16;
typedef short s8v __attribute__((ext_vector_type(8)));
typedef float f4v __attribute__((ext_vector_type(4)));

__device__ inline float b2f(bf16 x) { return __bfloat162float(x); }
__device__ inline float u2f(unsigned short u) { return __uint_as_float((unsigned)u << 16); }

// flag f: 1 = raw inputs are bf16, 0 = raw inputs are fp32. idx in ELEMENTS.
__device__ inline float ldw(const void* p, unsigned i, int f) {
    return f ? b2f(((const bf16*)p)[i]) : ((const float*)p)[i];
}

// order-preserving float->u32 (monotonic)
__device__ inline unsigned f2ord(float s) {
    unsigned u = __float_as_uint(s);
    return u ^ ((unsigned)((int)u >> 31) | 0x80000000u);
}

// popcount of mask bits strictly below this lane
__device__ inline int popc_lt(unsigned long long m) {
    return (int)__builtin_amdgcn_mbcnt_hi((unsigned)(m >> 32),
            __builtin_amdgcn_mbcnt_lo((unsigned)m, 0u));
}

// async global->LDS, 16 B per lane; lds dst must be wave-uniform (lane i lands at dst+16*i)
__device__ inline void gl_lds16(const short* g, short* l) {
    __builtin_amdgcn_global_load_lds(
        (const __attribute__((address_space(1))) unsigned int*)g,
        (__attribute__((address_space(3))) unsigned int*)l,
        16, 0, 0);
}

// ---------------- dtype sniffer ----------------
__global__ __launch_bounds__(256) void sniff_k(const unsigned* __restrict__ x, int nwords,
                                               int* __restrict__ flag) {
    __shared__ int red[4];
    const int t = threadIdx.x;
    int c = 0;
    for (int i = t; i < nwords; i += 256) c += ((x[i] & 0x7F80u) == 0x3F80u) ? 1 : 0;
    #pragma unroll
    for (int o = 32; o > 0; o >>= 1) c += __shfl_down(c, o);
    __syncthreads();
    if ((t & 63) == 0) red[t >> 6] = c;
    __syncthreads();
    if (t == 0) flag[0] = (red[0] + red[1] + red[2] + red[3] > nwords / 20) ? 1 : 0;
}

// ---------------- reductions (blockDim == 256) ----------------
__device__ inline float block_sum256(float v, float* red) {
    #pragma unroll
    for (int o = 32; o > 0; o >>= 1) v += __shfl_down(v, o);
    __syncthreads();
    if ((threadIdx.x & 63) == 0) red[threadIdx.x >> 6] = v;
    __syncthreads();
    return red[0] + red[1] + red[2] + red[3];
}

// ---------------- embedding ----------------
__global__ __launch_bounds__(256) void embed_k(
    const void* __restrict__ xv, const void* __restrict__ vw, const void* __restrict__ vb,
    const void* __restrict__ xm, const void* __restrict__ mw, const void* __restrict__ mb,
    bf16* __restrict__ Out, int rows, int Cv, int Cm, const int* __restrict__ flagp)
{
    const int f = *flagp;
    int i = blockIdx.x * 256 + threadIdx.x;
    if (i >= rows * DM) return;
    const int r = i >> 9, d = i & 511;
    float acc = ldw(vb, d, f) + ldw(mb, d, f);
    for (int c = 0; c < Cv; ++c) acc += ldw(xv, r * Cv + c, f) * ldw(vw, c * DM + d, f);
    for (int c = 0; c < Cm; ++c) acc += ldw(xm, r * Cm + c, f) * ldw(mw, c * DM + d, f);
    Out[i] = __float2bfloat16(acc);
}

// ---------------- weight transpose: raw [K][N] -> bf16 [N][K]; z batches sub-mats ----------------
__global__ __launch_bounds__(256) void transp_k(
    const void* __restrict__ W, unsigned off, unsigned zstride, bf16* __restrict__ out,
    int K, int N, const int* __restrict__ flagp)
{
    __shared__ float tile[32][33];
    const int f = *flagp;
    const unsigned zo = blockIdx.z * zstride;
    const int t = threadIdx.x;
    const int tx = t & 31, ty = t >> 5;               // 32 x 8
    const int n0 = blockIdx.x * 32, k0 = blockIdx.y * 32;
    #pragma unroll
    for (int i = 0; i < 4; ++i)
        tile[ty + 8 * i][tx] = ldw(W, off + zo + (unsigned)(k0 + ty + 8 * i) * N + n0 + tx, f);
    __syncthreads();
    #pragma unroll
    for (int i = 0; i < 4; ++i)
        out[(size_t)zo + (size_t)(n0 + ty + 8 * i) * K + k0 + tx] = __float2bfloat16(tile[tx][ty + 8 * i]);
}

// ---------------- MFMA GEMM 128x128 (256 thr): C = A[M,K]@Wt[N,K]^T + bias ----------------
// Staging via global_load_lds (16 B/lane), unpadded [row][32]-short LDS tiles.
template<bool G3, bool RELU>
__global__ __launch_bounds__(256) void mgemm_k(
    const short* __restrict__ A, const int* __restrict__ ridx,
    const short* __restrict__ Wt,
    const void* __restrict__ bias, unsigned boff0,
    bf16* __restrict__ C, int M, int N, int K, int lda, int ldc,
    const int* __restrict__ flagp)
{
    __shared__ short As[128 * 32];
    __shared__ short Ws[128 * 32];
    const int t = threadIdx.x;
    const int bm = blockIdx.y * 128, bn = blockIdx.x * 128;
    const int lane = t & 63, wave = t >> 6;
    const int mbase = (wave >> 1) * 64, nbase = (wave & 1) * 64;
    const int l15 = lane & 15, quad = lane >> 4;
    const int lrow = lane >> 2, lk = (lane & 3) * 8;

    f4v acc[4][4] = {};

    for (int k0 = 0; k0 < K; k0 += 32) {
        __syncthreads();
        #pragma unroll
        for (int j = 0; j < 2; ++j) {
            const int rb = wave * 32 + j * 16;
            const int row = bm + rb + lrow;
            const int rowc = row < M ? row : M - 1;
            const short* g;
            if (G3) {
                const int r = ridx[(k0 >> 9) * M + rowc];
                g = A + (size_t)r * lda + (k0 & 511) + lk;
            } else {
                g = A + (size_t)rowc * lda + k0 + lk;
            }
            gl_lds16(g, &As[rb * 32]);
        }
        #pragma unroll
        for (int j = 0; j < 2; ++j) {
            const int nb = wave * 32 + j * 16;
            gl_lds16(Wt + (size_t)(bn + nb + lrow) * K + k0 + lk, &Ws[nb * 32]);
        }
        __syncthreads();
        s8v af[4], bfv[4];
        #pragma unroll
        for (int i = 0; i < 4; ++i) {
            af[i]  = *(const s8v*)&As[(mbase + i * 16 + l15) * 32 + quad * 8];
            bfv[i] = *(const s8v*)&Ws[(nbase + i * 16 + l15) * 32 + quad * 8];
        }
        #pragma unroll
        for (int mi = 0; mi < 4; ++mi)
            #pragma unroll
            for (int ni = 0; ni < 4; ++ni)
                acc[mi][ni] = __builtin_amdgcn_mfma_f32_16x16x32_bf16(
                    af[mi], bfv[ni], acc[mi][ni], 0, 0, 0);
    }

    const int f = *flagp;
    float bv[4];
    #pragma unroll
    for (int ni = 0; ni < 4; ++ni)
        bv[ni] = ldw(bias, boff0 + (unsigned)(bn + nbase + ni * 16 + l15), f);

    #pragma unroll
    for (int mi = 0; mi < 4; ++mi) {
        #pragma unroll
        for (int r = 0; r < 4; ++r) {
            const int row = bm + mbase + mi * 16 + quad * 4 + r;
            if (row < M) {
                #pragma unroll
                for (int ni = 0; ni < 4; ++ni) {
                    float o = acc[mi][ni][r] + bv[ni];
                    if (RELU) o = fmaxf(o, 0.f);
                    C[(size_t)row * ldc + bn + nbase + ni * 16 + l15] = __float2bfloat16(o);
                }
            }
        }
    }
}

// ---------------- MFMA GEMM 128x64 (128 thr, 2 waves): for N=512-class GEMMs ----------------
template<bool G3, bool RELU>
__global__ __launch_bounds__(128) void mgemm64_k(
    const short* __restrict__ A, const int* __restrict__ ridx,
    const short* __restrict__ Wt,
    const void* __restrict__ bias, unsigned boff0,
    bf16* __restrict__ C, int M, int N, int K, int lda, int ldc,
    const int* __restrict__ flagp)
{
    __shared__ short As[128 * 32];
    __shared__ short Ws[64 * 32];
    const int t = threadIdx.x;
    const int bm = blockIdx.y * 128, bn = blockIdx.x * 64;
    const int lane = t & 63, wave = t >> 6;
    const int mbase = wave * 64;
    const int l15 = lane & 15, quad = lane >> 4;
    const int lrow = lane >> 2, lk = (lane & 3) * 8;

    f4v acc[4][4] = {};

    for (int k0 = 0; k0 < K; k0 += 32) {
        __syncthreads();
        #pragma unroll
        for (int j = 0; j < 4; ++j) {
            const int rb = wave * 64 + j * 16;
            const int row = bm + rb + lrow;
            const int rowc = row < M ? row : M - 1;
            const short* g;
            if (G3) {
                const int r = ridx[(k0 >> 9) * M + rowc];
                g = A + (size_t)r * lda + (k0 & 511) + lk;
            } else {
                g = A + (size_t)rowc * lda + k0 + lk;
            }
            gl_lds16(g, &As[rb * 32]);
        }
        #pragma unroll
        for (int j = 0; j < 2; ++j) {
            const int nb = wave * 32 + j * 16;
            gl_lds16(Wt + (size_t)(bn + nb + lrow) * K + k0 + lk, &Ws[nb * 32]);
        }
        __syncthreads();
        s8v af[4], bfv[4];
        #pragma unroll
        for (int i = 0; i < 4; ++i) {
            af[i]  = *(const s8v*)&As[(mbase + i * 16 + l15) * 32 + quad * 8];
            bfv[i] = *(const s8v*)&Ws[(i * 16 + l15) * 32 + quad * 8];
        }
        #pragma unroll
        for (int mi = 0; mi < 4; ++mi)
            #pragma unroll
            for (int ni = 0; ni < 4; ++ni)
                acc[mi][ni] = __builtin_amdgcn_mfma_f32_16x16x32_bf16(
                    af[mi], bfv[ni], acc[mi][ni], 0, 0, 0);
    }

    const int f = *flagp;
    float bv[4];
    #pragma unroll
    for (int ni = 0; ni < 4; ++ni)
        bv[ni] = ldw(bias, boff0 + (unsigned)(bn + ni * 16 + l15), f);

    #pragma unroll
    for (int mi = 0; mi < 4; ++mi) {
        #pragma unroll
        for (int r = 0; r < 4; ++r) {
            const int row = bm + mbase + mi * 16 + quad * 4 + r;
            if (row < M) {
                #pragma unroll
                for (int ni = 0; ni < 4; ++ni) {
                    float o = acc[mi][ni][r] + bv[ni];
                    if (RELU) o = fmaxf(o, 0.f);
                    C[(size_t)row * ldc + bn + ni * 16 + l15] = __float2bfloat16(o);
                }
            }
        }
    }
}

// ---------------- fused tile attention (strided q/k/v), 1024 threads ----------------
// MODE 0: ProbSparse top-16. MODE 1: causal. MODE 2: plain cross.
// 16 waves: phase 1 = MFMA QK^T with direct-global K frags (disjoint 16-col chunks/wave);
// phase 2+3 = one wave per query row (lane = head dim).
// MODE 0 selection: full-32-bit ballot radix-select (keys distinct -> exact count 16,
// single-class compaction == round-9 top-16 set), then 16 independent V loads.
template<int MODE>
__global__ __launch_bounds__(1024, 8) void fattn_k(
    bf16* __restrict__ q, const bf16* __restrict__ k, const bf16* __restrict__ v,
    int ldq, int ldkv, int Lq, int Lk)
{
    __shared__ short Qs[16 * 72];
    __shared__ float S[16 * 516];
    __shared__ int   PC[16][16];
    __shared__ float PE[16][16];

    const int t = threadIdx.x;
    const int q0 = blockIdx.x * 16, h = blockIdx.y, b = blockIdx.z;
    const int lane = t & 63, wave = t >> 6;
    const int l15 = lane & 15, quad = lane >> 4;

    const int qv = (Lq - q0) < 16 ? (Lq - q0) : 16;

    const bf16* Kbase = k + (size_t)b * Lk * ldkv + h * DK;
    const bf16* Vbase = v + (size_t)b * Lk * ldkv + h * DK;
    bf16* Qbase = q + (size_t)(b * Lq + q0) * ldq + h * DK;

    const int kmax = (MODE == 1) ? (q0 + 16 < Lk ? q0 + 16 : Lk) : Lk;
    const int ntile = (kmax + 63) >> 6;
    const int kpad = ntile << 6;
    const int nchunk = kpad >> 4;

    if (t < 128) {
        const int qr = t >> 3;
        const int qsrc = qr < qv ? qr : qv - 1;
        *(s8v*)&Qs[qr * 72 + (t & 7) * 8] =
            *(const s8v*)(Qbase + (size_t)qsrc * ldq + (t & 7) * 8);
    }
    __syncthreads();

    // ---- phase 1: S = QK^T / 8 (+ masks). wave w owns col chunks c = w, w+16, ... ----
    {
        const s8v a0 = *(const s8v*)&Qs[l15 * 72 + quad * 8];
        const s8v a1 = *(const s8v*)&Qs[l15 * 72 + 32 + quad * 8];
        for (int c = wave; c < nchunk; c += 16) {
            int srow = c * 16 + l15; if (srow >= Lk) srow = Lk - 1;
            const bf16* kp = Kbase + (size_t)srow * ldkv + quad * 8;
            const s8v b0 = *(const s8v*)kp;
            const s8v b1 = *(const s8v*)(kp + 32);
            f4v acc = {0.f, 0.f, 0.f, 0.f};
            acc = __builtin_amdgcn_mfma_f32_16x16x32_bf16(a0, b0, acc, 0, 0, 0);
            acc = __builtin_amdgcn_mfma_f32_16x16x32_bf16(a1, b1, acc, 0, 0, 0);
            const int colg = c * 16 + l15;
            #pragma unroll
            for (int r = 0; r < 4; ++r) {
                const int qrow = quad * 4 + r;
                float s = acc[r] * 0.125f;
                if (colg >= Lk) s = -1e9f;
                if (MODE == 1 && colg > q0 + qrow) s = -1e9f;
                S[qrow * 516 + colg] = s;
            }
        }
    }
    __syncthreads();

    // ---- phase 2+3 fused: one wave per query row; lane = output dim ----
    const int row = wave;
    float a = 0.f;
    float inv;
    if (MODE == 0) {
        // packed keys: 23-bit quantized score | 9-bit col; 0 for padded cols
        // (col >= kpad reads uninitialized S -- the round-10 bug; guard restored)
        unsigned key[8];
        #pragma unroll
        for (int j = 0; j < 8; ++j) {
            const int col = lane + 64 * j;
            key[j] = (col < kpad)
                ? ((f2ord(S[row * 516 + col]) & 0xFFFFFE00u) | (unsigned)col)
                : 0u;
        }
        // row max (exp offset): one butterfly over per-lane max
        unsigned km = key[0];
        #pragma unroll
        for (int j = 1; j < 8; ++j) km = km > key[j] ? km : key[j];
        #pragma unroll
        for (int off = 1; off < 64; off <<= 1) {
            const unsigned o = __shfl_xor(km, off);
            km = km > o ? km : o;
        }
        const float mr = S[row * 516 + (int)(km & 511u)];

        // full-32-bit binary search: largest T with count(key >= T) >= 16.
        // Keys distinct (col bits) -> terminates with count exactly 16.
        // Counting via ballot + popc (scalar pipe); early exit on c == 16.
        unsigned T = 0u;
        for (int bbit = 31; bbit >= 0; --bbit) {
            const unsigned T2 = T | (1u << bbit);
            int c = 0;
            #pragma unroll
            for (int j = 0; j < 8; ++j)
                c += (int)__popcll(__ballot(key[j] >= T2));
            if (c >= 16) {
                T = T2;
                if (c == 16) break;
            }
        }

        // single-class compaction: exactly the 16 keys >= T -> (col, e) pairs in LDS
        int cnt = 0;
        #pragma unroll
        for (int j = 0; j < 8; ++j) {
            const bool s = key[j] >= T;
            const unsigned long long bal = __ballot(s);
            if (s) {
                const int p = cnt + popc_lt(bal);
                const int col = (int)(key[j] & 511u);
                PC[row][p] = col;
                PE[row][p] = expf(S[row * 516 + col] - mr);
            }
            cnt += (int)__popcll(bal);
        }
        // wave-private row: same-wave DS ops execute in order; no barrier needed

        float den = 0.f;
        #pragma unroll
        for (int it = 0; it < 16; ++it) {
            const int col = PC[row][it];      // broadcast
            const float e = PE[row][it];
            den += e;
            a += e * b2f(Vbase[(size_t)col * ldkv + lane]);
        }
        inv = 1.f / den;
    } else {
        float lv = -INFINITY;
        #pragma unroll
        for (int j = 0; j < 8; ++j) {
            const int col = lane + 64 * j;
            if (col < kpad) lv = fmaxf(lv, S[row * 516 + col]);
        }
        #pragma unroll
        for (int off = 1; off < 64; off <<= 1) lv = fmaxf(lv, __shfl_xor(lv, off));
        float part = 0.f;
        #pragma unroll
        for (int j = 0; j < 8; ++j) {
            const int col = lane + 64 * j;
            if (col < kpad) {
                const float w = expf(S[row * 516 + col] - lv);
                S[row * 516 + col] = w;
                part += w;
            }
        }
        #pragma unroll
        for (int off = 1; off < 64; off <<= 1) part += __shfl_xor(part, off);
        inv = 1.f / part;
        const int kend = (MODE == 1) ? (q0 + row + 1 < kmax ? q0 + row + 1 : kmax) : kmax;
        #pragma unroll 4
        for (int k2 = 0; k2 < kend; ++k2)
            a += S[row * 516 + k2] * b2f(Vbase[(size_t)k2 * ldkv + lane]);
    }
    if (row < qv)
        Qbase[(size_t)row * ldq + lane] = __float2bfloat16(a * inv);
}

// ---------------- layernorm over D=512, optional residual; in-place safe ----------------
__global__ __launch_bounds__(256) void ln_off_k(
    const bf16* __restrict__ X, const bf16* __restrict__ R,
    const void* __restrict__ gb, unsigned goff,
    bf16* __restrict__ Out, const int* __restrict__ flagp)
{
    __shared__ float red[4];
    const int f = *flagp;
    const int t = threadIdx.x;
    const size_t base = (size_t)blockIdx.x * DM;
    float v0 = b2f(X[base + t]), v1 = b2f(X[base + t + 256]);
    if (R) { v0 += b2f(R[base + t]); v1 += b2f(R[base + t + 256]); }
    const float mean = block_sum256(v0 + v1, red) * (1.f / 512.f);
    const float d0 = v0 - mean, d1 = v1 - mean;
    const float var = block_sum256(d0 * d0 + d1 * d1, red) * (1.f / 512.f);
    const float rstd = rsqrtf(var + 1e-5f);
    Out[base + t]       = __float2bfloat16(d0 * rstd * ldw(gb, goff + t, f)       + ldw(gb, goff + 512 + t, f));
    Out[base + t + 256] = __float2bfloat16(d1 * rstd * ldw(gb, goff + t + 256, f) + ldw(gb, goff + 768 + t, f));
}

// ---------------- conv distill helpers ----------------
// conv weights w[2][o][c][j] -> transposed GEMM layout wt[layer][o][j*512+c]
__global__ __launch_bounds__(256) void convw_k(const void* __restrict__ w,
                                               bf16* __restrict__ wt, int total,
                                               const int* __restrict__ flagp) {
    const int f = *flagp;
    int i = blockIdx.x * 256 + threadIdx.x;
    if (i >= total) return;
    const int layer = i / 786432, rem2 = i % 786432;
    const int o = rem2 / 1536, rem = rem2 % 1536;
    const int j = rem >> 9, c = rem & 511;
    wt[i] = __float2bfloat16(ldw(w, (unsigned)layer * 786432u + (unsigned)(o * 512 + c) * 3 + j, f));
}

__global__ __launch_bounds__(256) void convidx_k(int* __restrict__ idx, int Lc, int L, int total) {
    int i = blockIdx.x * 256 + threadIdx.x;
    if (i >= total) return;
    const int j = i / (16 * Lc), mrem = i % (16 * Lc);
    const int b = mrem / Lc, l = mrem % Lc;
    int src = l + j - 2;
    src %= L; if (src < 0) src += L;
    idx[i] = b * L + src;
}

__global__ __launch_bounds__(256) void bnstat1_k(const bf16* __restrict__ Y, float* __restrict__ part, int M) {
    const int t = threadIdx.x;
    float s0 = 0.f, q0 = 0.f, s1 = 0.f, q1 = 0.f;
    for (int r = blockIdx.x; r < M; r += gridDim.x) {
        const ushort2 u = *reinterpret_cast<const ushort2*>(Y + (size_t)r * DM + t * 2);
        const float a = u2f(u.x), c = u2f(u.y);
        s0 += a; q0 += a * a;
        s1 += c; q1 += c * c;
    }
    float* p = part + (size_t)blockIdx.x * 1024;
    p[2 * t] = s0; p[2 * t + 1] = s1;
    p[512 + 2 * t] = q0; p[512 + 2 * t + 1] = q1;
}

__global__ __launch_bounds__(256) void bnstat2_k(const float* __restrict__ part, float* __restrict__ stats,
                                                 int nchunk, int M) {
    const int ch = blockIdx.x * 256 + threadIdx.x;
    if (ch >= 512) return;
    float S = 0.f, Qs = 0.f;
    for (int c = 0; c < nchunk; ++c) { S += part[c * 1024 + ch]; Qs += part[c * 1024 + 512 + ch]; }
    const float mean = S / (float)M;
    const float var = Qs / (float)M - mean * mean;
    stats[ch] = mean;
    stats[512 + ch] = fmaxf(var, 0.f);
}

__global__ __launch_bounds__(256) void bnpool_k(
    const bf16* __restrict__ Yc, const float* __restrict__ stats,
    const void* __restrict__ g, const void* __restrict__ bb, unsigned off,
    bf16* __restrict__ Out, int Lc, int Lout, int total, const int* __restrict__ flagp)
{
    const int f = *flagp;
    int i = blockIdx.x * 256 + threadIdx.x;
    if (i >= total) return;
    const int ch = i & 511;
    const int lp = (i >> 9) % Lout;
    const int b = i / (512 * Lout);
    const float mean = stats[ch], var = stats[512 + ch];
    const float sc = ldw(g, off + ch, f) * rsqrtf(var + 1e-5f);
    const float sh = ldw(bb, off + ch, f) - mean * sc;
    float mx = -INFINITY;
    const int l0 = 2 * lp - 1;
    #pragma unroll
    for (int d = 0; d < 3; ++d) {
        const int l = l0 + d;
        if (l >= 0 && l < Lc) {
            float v = b2f(Yc[((size_t)b * Lc + l) * DM + ch]) * sc + sh;
            v = v > 0.f ? v : expm1f(v);  // ELU
            mx = fmaxf(mx, v);
        }
    }
    Out[((size_t)b * Lout + lp) * DM + ch] = __float2bfloat16(mx);
}

// ---------------- final projection to CO=7, dtype-matched store ----------------
__global__ __launch_bounds__(256) void fc_k(
    const bf16* __restrict__ Yn, const void* __restrict__ fcw, const void* __restrict__ fcb,
    void* __restrict__ out, int total, const int* __restrict__ flagp)
{
    const int f = *flagp;
    int i = blockIdx.x * 256 + threadIdx.x;
    if (i >= total) return;
    const int r = i / 7, co = i % 7;
    const bf16* yr = Yn + (size_t)r * DM;
    float acc = ldw(fcb, co, f);
    for (int d = 0; d < DM; ++d) acc += b2f(yr[d]) * ldw(fcw, d * 7 + co, f);
    if (f) ((bf16*)out)[i] = __float2bfloat16(acc);
    else   ((float*)out)[i] = acc;
}

// =============================================================================
extern "C" void kernel_launch(void* const* d_in, const int* in_sizes, int n_in,
                              void* d_out, int out_size, void* d_ws, size_t ws_size,
                              hipStream_t stream)
{
    const void* x_enc      = d_in[0];
    const void* x_mark_enc = d_in[1];
    const void* x_dec      = d_in[2];
    const void* x_mark_dec = d_in[3];
    const void* enc_vw = d_in[4];
    const void* enc_vb = d_in[5];
    const void* enc_mw = d_in[6];
    const void* enc_mb = d_in[7];
    const void* dec_vw = d_in[8];
    const void* dec_vb = d_in[9];
    const void* dec_mw = d_in[10];
    const void* dec_mb = d_in[11];
    const void* eW    = d_in[12];
    const void* ebi   = d_in[13];
    const void* effw1 = d_in[14];
    const void* effb1 = d_in[15];
    const void* effw2 = d_in[16];
    const void* effb2 = d_in[17];
    const void* eln1  = d_in[18];
    const void* eln2  = d_in[19];
    const void* cw    = d_in[20];
    const void* cb    = d_in[21];
    const void* cbn_g = d_in[22];
    const void* cbn_b = d_in[23];
    const void* enc_norm = d_in[24];
    const void* dsW   = d_in[25];
    const void* dsb   = d_in[26];
    const void* dcW   = d_in[27];
    const void* dcb   = d_in[28];
    const void* dffw1 = d_in[29];
    const void* dffb1 = d_in[30];
    const void* dffw2 = d_in[31];
    const void* dffb2 = d_in[32];
    const void* dln   = d_in[33];
    const void* dec_norm = d_in[34];
    const void* fcw   = d_in[35];
    const void* fcb   = d_in[36];

    // ---- workspace layout (~90 MiB; 111 MiB footprint ran clean in round 1) ----
    // X    [0, 8M)      : encoder acts; MEM + Yd in decoder phase
    // QKV  [8M, 40M)    : fused QKV / FFN hidden (aliased) / conv out / cross CQ+CKV
    // OUT  [40M, 48M)   : O-proj / FFN2 dest
    // WT   [48M, ~86.8M): ALL transposed weights (one-time prologue)
    // misc [88M, ~90M)  : IDX0/IDX1, PART, STATS, FLAG
    char* wsp = (char*)d_ws;
    bf16* X    = (bf16*)wsp;
    bf16* QKV  = (bf16*)(wsp + ((size_t)8 << 20));
    bf16* HID  = QKV;                                 // FFN hidden aliases dead QKV
    bf16* OUT  = (bf16*)(wsp + ((size_t)40 << 20));
    bf16* WT   = (bf16*)(wsp + ((size_t)48 << 20));
    int*   IDX0 = (int*)(wsp + ((size_t)88 << 20));   // 3*16*514 = 24672 ints
    int*   IDX1 = IDX0 + 24672;                       // 3*16*259 = 12432 ints
    float* PART = (float*)(wsp + ((size_t)89 << 20));
    float* STATS= (float*)(wsp + ((size_t)89 << 20) + (1 << 18));
    int*   FLAG = (int*)(wsp + ((size_t)89 << 20) + (1 << 18) + 4096);
    bf16* MEMb = X;                                               // [2080][512]
    bf16* Yd   = (bf16*)(wsp + (size_t)16 * 130 * 512 * 2);       // [4096][512]

    // transposed weight sub-arenas (element offsets)
    bf16* WTE  = WT;                    // enc QKVO: (i*4+q)*262144
    bf16* EW1T = WT + 3145728;          // + i*1048576
    bf16* EW2T = WT + 6291456;          // + i*1048576
    bf16* CWT  = WT + 9437184;          // + i*786432
    bf16* DSWt = WT + 11010048;         // + (i*4+q)*262144
    bf16* DCWt = WT + 13107200;
    bf16* DW1T = WT + 15204352;
    bf16* DW2T = WT + 17301504;

    auto cdiv = [](int a, int b) { return (a + b - 1) / b; };
    auto gemm = [&](const bf16* A, const bf16* Wt, const void* bias, unsigned boff,
                    bf16* C, int M, int N, int K, int lda, int ldc, bool relu) {
        dim3 g(N / 128, cdiv(M, 128));
        if (relu) mgemm_k<false, true><<<g, 256, 0, stream>>>(
            (const short*)A, nullptr, (const short*)Wt, bias, boff, C, M, N, K, lda, ldc, FLAG);
        else      mgemm_k<false, false><<<g, 256, 0, stream>>>(
            (const short*)A, nullptr, (const short*)Wt, bias, boff, C, M, N, K, lda, ldc, FLAG);
    };
    auto gemm64 = [&](const bf16* A, const bf16* Wt, const void* bias, unsigned boff,
                      bf16* C, int M, int N, int K, int lda, int ldc) {
        dim3 g(N / 64, cdiv(M, 128));
        mgemm64_k<false, false><<<g, 128, 0, stream>>>(
            (const short*)A, nullptr, (const short*)Wt, bias, boff, C, M, N, K, lda, ldc, FLAG);
    };
    auto transp = [&](const void* W, unsigned zstride, int nz, bf16* out, int K, int N) {
        transp_k<<<dim3(N / 32, K / 32, nz), 256, 0, stream>>>(W, 0u, zstride, out, K, N, FLAG);
    };

    // ---- prologue: sniff, all weight transposes, conv indices, embeddings ----
    sniff_k<<<1, 256, 0, stream>>>((const unsigned*)x_mark_enc, 16384, FLAG);
    transp(eW,    262144u, 12, WTE,  512, 512);
    transp(effw1, 1048576u, 3, EW1T, 512, 2048);
    transp(effw2, 1048576u, 3, EW2T, 2048, 512);
    convw_k<<<cdiv(1572864, 256), 256, 0, stream>>>(cw, CWT, 1572864, FLAG);
    transp(dsW,   262144u, 8, DSWt, 512, 512);
    transp(dcW,   262144u, 8, DCWt, 512, 512);
    transp(dffw1, 1048576u, 2, DW1T, 512, 2048);
    transp(dffw2, 1048576u, 2, DW2T, 2048, 512);
    convidx_k<<<cdiv(24672, 256), 256, 0, stream>>>(IDX0, 514, 512, 24672);
    convidx_k<<<cdiv(12432, 256), 256, 0, stream>>>(IDX1, 259, 257, 12432);
    embed_k<<<cdiv(16 * 512 * 512, 256), 256, 0, stream>>>(
        x_enc, enc_vw, enc_vb, x_mark_enc, enc_mw, enc_mb, X, 16 * 512, 7, 4, FLAG);

    // ---- encoder ----
    int L = 512;
    for (int i = 0; i < 3; ++i) {
        const int rows = 16 * L;
        const unsigned b0 = (unsigned)i * 4u * 512u;
        gemm(X, WTE + (size_t)i * 4 * 262144, ebi, b0, QKV, rows, 1536, 512, 512, 1536, false);
        fattn_k<0><<<dim3(cdiv(L, 16), 8, 16), 1024, 0, stream>>>(
            QKV, QKV + 512, QKV + 1024, 1536, 1536, L, L);
        gemm64(QKV, WTE + (size_t)(i * 4 + 3) * 262144, ebi, b0 + 1536u, OUT, rows, 512, 512, 1536, 512);
        ln_off_k<<<rows, 256, 0, stream>>>(X, OUT, eln1, (unsigned)i * 1024u, X, FLAG);

        gemm(X, EW1T + (size_t)i * 1048576, effb1, (unsigned)i * 2048u, HID, rows, 2048, 512, 512, 2048, true);
        gemm64(HID, EW2T + (size_t)i * 1048576, effb2, (unsigned)i * 512u, OUT, rows, 512, 2048, 2048, 512);
        ln_off_k<<<rows, 256, 0, stream>>>(X, OUT, eln2, (unsigned)i * 1024u, X, FLAG);

        if (i < 2) {
            const int Lc = L + 2, Mc = 16 * Lc;
            const int* IDXi = (i == 0) ? IDX0 : IDX1;
            mgemm64_k<true, false><<<dim3(8, cdiv(Mc, 128)), 128, 0, stream>>>(
                (const short*)X, IDXi, (const short*)(CWT + (size_t)i * 786432),
                cb, (unsigned)i * 512u, QKV, Mc, 512, 1536, 512, 512, FLAG);
            bnstat1_k<<<32, 256, 0, stream>>>(QKV, PART, Mc);
            bnstat2_k<<<2, 256, 0, stream>>>(PART, STATS, 32, Mc);
            const int Lout = (L + 1) / 2 + 1;   // 514->257, 259->130
            const int tot = 16 * Lout * 512;
            bnpool_k<<<cdiv(tot, 256), 256, 0, stream>>>(
                QKV, STATS, cbn_g, cbn_b, (unsigned)i * 512u, X, Lc, Lout, tot, FLAG);
            L = Lout;
        }
    }
    const int Lm = L;  // 130
    ln_off_k<<<16 * Lm, 256, 0, stream>>>(X, nullptr, enc_norm, 0u, MEMb, FLAG);

    // ---- decoder embedding ----
    const int rowsD = 16 * 256;
    embed_k<<<cdiv(rowsD * 512, 256), 256, 0, stream>>>(
        x_dec, dec_vw, dec_vb, x_mark_dec, dec_mw, dec_mb, Yd, rowsD, 7, 4, FLAG);

    // ---- decoder ----
    bf16* CQ  = QKV;                       // [4096][512]
    bf16* CKV = QKV + (size_t)4096 * 512;  // [2080][1024]
    for (int i = 0; i < 2; ++i) {
        const unsigned b0 = (unsigned)i * 4u * 512u;
        // self-attention
        gemm(Yd, DSWt + (size_t)i * 4 * 262144, dsb, b0, QKV, rowsD, 1536, 512, 512, 1536, false);
        fattn_k<1><<<dim3(16, 8, 16), 1024, 0, stream>>>(
            QKV, QKV + 512, QKV + 1024, 1536, 1536, 256, 256);
        gemm64(QKV, DSWt + (size_t)(i * 4 + 3) * 262144, dsb, b0 + 1536u, OUT, rowsD, 512, 512, 1536, 512);
        ln_off_k<<<rowsD, 256, 0, stream>>>(Yd, OUT, dln, (unsigned)(i * 3 + 0) * 1024u, Yd, FLAG);

        // cross-attention
        gemm64(Yd, DCWt + (size_t)i * 4 * 262144, dcb, b0, CQ, rowsD, 512, 512, 512, 512);
        gemm(MEMb, DCWt + (size_t)(i * 4 + 1) * 262144, dcb, b0 + 512u, CKV, 16 * Lm, 1024, 512, 512, 1024, false);
        fattn_k<2><<<dim3(16, 8, 16), 1024, 0, stream>>>(
            CQ, CKV, CKV + 512, 512, 1024, 256, Lm);
        gemm64(CQ, DCWt + (size_t)(i * 4 + 3) * 262144, dcb, b0 + 1536u, OUT, rowsD, 512, 512, 512, 512);
        ln_off_k<<<rowsD, 256, 0, stream>>>(Yd, OUT, dln, (unsigned)(i * 3 + 1) * 1024u, Yd, FLAG);

        // FFN
        gemm(Yd, DW1T + (size_t)i * 1048576, dffb1, (unsigned)i * 2048u, HID, rowsD, 2048, 512, 512, 2048, true);
        gemm64(HID, DW2T + (size_t)i * 1048576, dffb2, (unsigned)i * 512u, OUT, rowsD, 512, 2048, 2048, 512);
        ln_off_k<<<rowsD, 256, 0, stream>>>(Yd, OUT, dln, (unsigned)(i * 3 + 2) * 1024u, Yd, FLAG);
    }

    ln_off_k<<<rowsD, 256, 0, stream>>>(Yd, nullptr, dec_norm, 0u, OUT, FLAG);
    fc_k<<<cdiv(rowsD * 7, 256), 256, 0, stream>>>(OUT, fcw, fcb, d_out, rowsD * 7, FLAG);
}

// Round 4
// 1727.146 us; speedup vs baseline: 1.1080x; 1.0282x over previous
//
#include <hip/hip_runtime.h>
#include <hip/hip_bf16.h>

// Informer forward, MI355X. Round 12: fattn 1024->512 threads (8 waves, 4 blocks/CU).
//  - Round-11 counters: fattn<0> 104.6 us, VALUBusy 31, MfmaUtil 0.24, HBM 4%,
//    Occupancy 46.5 -> latency-bound; 16-wave barrier groups pack only ~1/CU effective.
//  - Fix: 512-thr blocks (same 16-row tile, grid unchanged): 4 independent blocks/CU
//    (LDS 36.5 KB, threads 2048), phase-1 2-deep K-load pipeline (2x MLP/wave),
//    phase 2/3 processes 2 rows per wave (row = wave + 8*rr). Selection math identical.
// Retained: ballot radix-select top-16 (round 11, passed absmax 0.0117), direct-global
// K frags, GEMM staging via global_load_lds (width=16), weight-transpose prologue,
// dtype sniffer, fused QKV (N=1536), mgemm64 for N=512.
// Round 11: passed, absmax 0.0117, 1775.9 us.
// B=16, LE=512, LD=256, D=512, H=8, dk=64, DFF=2048, NE=3, ND=2, TOPK=16.
// Encoder lengths: 512 -> conv(514)/pool -> 257 -> conv(259)/pool -> 130.

#define DM 512
#define DK 64

using bf16 = __hip_bfloat16;
typedef short s8v __attribute__((ext_vector_type(8)));
typedef float f4v __attribute__((ext_vector_type(4)));

__device__ inline float b2f(bf16 x) { return __bfloat162float(x); }
__device__ inline float u2f(unsigned short u) { return __uint_as_float((unsigned)u << 16); }

// flag f: 1 = raw inputs are bf16, 0 = raw inputs are fp32. idx in ELEMENTS.
__device__ inline float ldw(const void* p, unsigned i, int f) {
    return f ? b2f(((const bf16*)p)[i]) : ((const float*)p)[i];
}

// order-preserving float->u32 (monotonic)
__device__ inline unsigned f2ord(float s) {
    unsigned u = __float_as_uint(s);
    return u ^ ((unsigned)((int)u >> 31) | 0x80000000u);
}

// popcount of mask bits strictly below this lane
__device__ inline int popc_lt(unsigned long long m) {
    return (int)__builtin_amdgcn_mbcnt_hi((unsigned)(m >> 32),
            __builtin_amdgcn_mbcnt_lo((unsigned)m, 0u));
}

// async global->LDS, 16 B per lane; lds dst must be wave-uniform (lane i lands at dst+16*i)
__device__ inline void gl_lds16(const short* g, short* l) {
    __builtin_amdgcn_global_load_lds(
        (const __attribute__((address_space(1))) unsigned int*)g,
        (__attribute__((address_space(3))) unsigned int*)l,
        16, 0, 0);
}

// ---------------- dtype sniffer ----------------
__global__ __launch_bounds__(256) void sniff_k(const unsigned* __restrict__ x, int nwords,
                                               int* __restrict__ flag) {
    __shared__ int red[4];
    const int t = threadIdx.x;
    int c = 0;
    for (int i = t; i < nwords; i += 256) c += ((x[i] & 0x7F80u) == 0x3F80u) ? 1 : 0;
    #pragma unroll
    for (int o = 32; o > 0; o >>= 1) c += __shfl_down(c, o);
    __syncthreads();
    if ((t & 63) == 0) red[t >> 6] = c;
    __syncthreads();
    if (t == 0) flag[0] = (red[0] + red[1] + red[2] + red[3] > nwords / 20) ? 1 : 0;
}

// ---------------- reductions (blockDim == 256) ----------------
__device__ inline float block_sum256(float v, float* red) {
    #pragma unroll
    for (int o = 32; o > 0; o >>= 1) v += __shfl_down(v, o);
    __syncthreads();
    if ((threadIdx.x & 63) == 0) red[threadIdx.x >> 6] = v;
    __syncthreads();
    return red[0] + red[1] + red[2] + red[3];
}

// ---------------- embedding ----------------
__global__ __launch_bounds__(256) void embed_k(
    const void* __restrict__ xv, const void* __restrict__ vw, const void* __restrict__ vb,
    const void* __restrict__ xm, const void* __restrict__ mw, const void* __restrict__ mb,
    bf16* __restrict__ Out, int rows, int Cv, int Cm, const int* __restrict__ flagp)
{
    const int f = *flagp;
    int i = blockIdx.x * 256 + threadIdx.x;
    if (i >= rows * DM) return;
    const int r = i >> 9, d = i & 511;
    float acc = ldw(vb, d, f) + ldw(mb, d, f);
    for (int c = 0; c < Cv; ++c) acc += ldw(xv, r * Cv + c, f) * ldw(vw, c * DM + d, f);
    for (int c = 0; c < Cm; ++c) acc += ldw(xm, r * Cm + c, f) * ldw(mw, c * DM + d, f);
    Out[i] = __float2bfloat16(acc);
}

// ---------------- weight transpose: raw [K][N] -> bf16 [N][K]; z batches sub-mats ----------------
__global__ __launch_bounds__(256) void transp_k(
    const void* __restrict__ W, unsigned off, unsigned zstride, bf16* __restrict__ out,
    int K, int N, const int* __restrict__ flagp)
{
    __shared__ float tile[32][33];
    const int f = *flagp;
    const unsigned zo = blockIdx.z * zstride;
    const int t = threadIdx.x;
    const int tx = t & 31, ty = t >> 5;               // 32 x 8
    const int n0 = blockIdx.x * 32, k0 = blockIdx.y * 32;
    #pragma unroll
    for (int i = 0; i < 4; ++i)
        tile[ty + 8 * i][tx] = ldw(W, off + zo + (unsigned)(k0 + ty + 8 * i) * N + n0 + tx, f);
    __syncthreads();
    #pragma unroll
    for (int i = 0; i < 4; ++i)
        out[(size_t)zo + (size_t)(n0 + ty + 8 * i) * K + k0 + tx] = __float2bfloat16(tile[tx][ty + 8 * i]);
}

// ---------------- MFMA GEMM 128x128 (256 thr): C = A[M,K]@Wt[N,K]^T + bias ----------------
// Staging via global_load_lds (16 B/lane), unpadded [row][32]-short LDS tiles.
template<bool G3, bool RELU>
__global__ __launch_bounds__(256) void mgemm_k(
    const short* __restrict__ A, const int* __restrict__ ridx,
    const short* __restrict__ Wt,
    const void* __restrict__ bias, unsigned boff0,
    bf16* __restrict__ C, int M, int N, int K, int lda, int ldc,
    const int* __restrict__ flagp)
{
    __shared__ short As[128 * 32];
    __shared__ short Ws[128 * 32];
    const int t = threadIdx.x;
    const int bm = blockIdx.y * 128, bn = blockIdx.x * 128;
    const int lane = t & 63, wave = t >> 6;
    const int mbase = (wave >> 1) * 64, nbase = (wave & 1) * 64;
    const int l15 = lane & 15, quad = lane >> 4;
    const int lrow = lane >> 2, lk = (lane & 3) * 8;

    f4v acc[4][4] = {};

    for (int k0 = 0; k0 < K; k0 += 32) {
        __syncthreads();
        #pragma unroll
        for (int j = 0; j < 2; ++j) {
            const int rb = wave * 32 + j * 16;
            const int row = bm + rb + lrow;
            const int rowc = row < M ? row : M - 1;
            const short* g;
            if (G3) {
                const int r = ridx[(k0 >> 9) * M + rowc];
                g = A + (size_t)r * lda + (k0 & 511) + lk;
            } else {
                g = A + (size_t)rowc * lda + k0 + lk;
            }
            gl_lds16(g, &As[rb * 32]);
        }
        #pragma unroll
        for (int j = 0; j < 2; ++j) {
            const int nb = wave * 32 + j * 16;
            gl_lds16(Wt + (size_t)(bn + nb + lrow) * K + k0 + lk, &Ws[nb * 32]);
        }
        __syncthreads();
        s8v af[4], bfv[4];
        #pragma unroll
        for (int i = 0; i < 4; ++i) {
            af[i]  = *(const s8v*)&As[(mbase + i * 16 + l15) * 32 + quad * 8];
            bfv[i] = *(const s8v*)&Ws[(nbase + i * 16 + l15) * 32 + quad * 8];
        }
        #pragma unroll
        for (int mi = 0; mi < 4; ++mi)
            #pragma unroll
            for (int ni = 0; ni < 4; ++ni)
                acc[mi][ni] = __builtin_amdgcn_mfma_f32_16x16x32_bf16(
                    af[mi], bfv[ni], acc[mi][ni], 0, 0, 0);
    }

    const int f = *flagp;
    float bv[4];
    #pragma unroll
    for (int ni = 0; ni < 4; ++ni)
        bv[ni] = ldw(bias, boff0 + (unsigned)(bn + nbase + ni * 16 + l15), f);

    #pragma unroll
    for (int mi = 0; mi < 4; ++mi) {
        #pragma unroll
        for (int r = 0; r < 4; ++r) {
            const int row = bm + mbase + mi * 16 + quad * 4 + r;
            if (row < M) {
                #pragma unroll
                for (int ni = 0; ni < 4; ++ni) {
                    float o = acc[mi][ni][r] + bv[ni];
                    if (RELU) o = fmaxf(o, 0.f);
                    C[(size_t)row * ldc + bn + nbase + ni * 16 + l15] = __float2bfloat16(o);
                }
            }
        }
    }
}

// ---------------- MFMA GEMM 128x64 (128 thr, 2 waves): for N=512-class GEMMs ----------------
template<bool G3, bool RELU>
__global__ __launch_bounds__(128) void mgemm64_k(
    const short* __restrict__ A, const int* __restrict__ ridx,
    const short* __restrict__ Wt,
    const void* __restrict__ bias, unsigned boff0,
    bf16* __restrict__ C, int M, int N, int K, int lda, int ldc,
    const int* __restrict__ flagp)
{
    __shared__ short As[128 * 32];
    __shared__ short Ws[64 * 32];
    const int t = threadIdx.x;
    const int bm = blockIdx.y * 128, bn = blockIdx.x * 64;
    const int lane = t & 63, wave = t >> 6;
    const int mbase = wave * 64;
    const int l15 = lane & 15, quad = lane >> 4;
    const int lrow = lane >> 2, lk = (lane & 3) * 8;

    f4v acc[4][4] = {};

    for (int k0 = 0; k0 < K; k0 += 32) {
        __syncthreads();
        #pragma unroll
        for (int j = 0; j < 4; ++j) {
            const int rb = wave * 64 + j * 16;
            const int row = bm + rb + lrow;
            const int rowc = row < M ? row : M - 1;
            const short* g;
            if (G3) {
                const int r = ridx[(k0 >> 9) * M + rowc];
                g = A + (size_t)r * lda + (k0 & 511) + lk;
            } else {
                g = A + (size_t)rowc * lda + k0 + lk;
            }
            gl_lds16(g, &As[rb * 32]);
        }
        #pragma unroll
        for (int j = 0; j < 2; ++j) {
            const int nb = wave * 32 + j * 16;
            gl_lds16(Wt + (size_t)(bn + nb + lrow) * K + k0 + lk, &Ws[nb * 32]);
        }
        __syncthreads();
        s8v af[4], bfv[4];
        #pragma unroll
        for (int i = 0; i < 4; ++i) {
            af[i]  = *(const s8v*)&As[(mbase + i * 16 + l15) * 32 + quad * 8];
            bfv[i] = *(const s8v*)&Ws[(i * 16 + l15) * 32 + quad * 8];
        }
        #pragma unroll
        for (int mi = 0; mi < 4; ++mi)
            #pragma unroll
            for (int ni = 0; ni < 4; ++ni)
                acc[mi][ni] = __builtin_amdgcn_mfma_f32_16x16x32_bf16(
                    af[mi], bfv[ni], acc[mi][ni], 0, 0, 0);
    }

    const int f = *flagp;
    float bv[4];
    #pragma unroll
    for (int ni = 0; ni < 4; ++ni)
        bv[ni] = ldw(bias, boff0 + (unsigned)(bn + ni * 16 + l15), f);

    #pragma unroll
    for (int mi = 0; mi < 4; ++mi) {
        #pragma unroll
        for (int r = 0; r < 4; ++r) {
            const int row = bm + mbase + mi * 16 + quad * 4 + r;
            if (row < M) {
                #pragma unroll
                for (int ni = 0; ni < 4; ++ni) {
                    float o = acc[mi][ni][r] + bv[ni];
                    if (RELU) o = fmaxf(o, 0.f);
                    C[(size_t)row * ldc + bn + ni * 16 + l15] = __float2bfloat16(o);
                }
            }
        }
    }
}

// ---------------- fused tile attention (strided q/k/v), 512 threads ----------------
// MODE 0: ProbSparse top-16. MODE 1: causal. MODE 2: plain cross.
// 8 waves, 4 blocks/CU: phase 1 = MFMA QK^T, direct-global K frags, 2-deep load
// pipeline, wave w owns col chunks c = w, w+8, ... ; phase 2+3 = 2 rows per wave
// (row = wave + 8*rr), lane = head dim.
// MODE 0 selection: full-32-bit ballot radix-select (keys distinct -> exact count 16).
template<int MODE>
__global__ __launch_bounds__(512, 8) void fattn_k(
    bf16* __restrict__ q, const bf16* __restrict__ k, const bf16* __restrict__ v,
    int ldq, int ldkv, int Lq, int Lk)
{
    __shared__ short Qs[16 * 72];
    __shared__ float S[16 * 516];
    __shared__ int   PC[16][16];
    __shared__ float PE[16][16];

    const int t = threadIdx.x;
    const int q0 = blockIdx.x * 16, h = blockIdx.y, b = blockIdx.z;
    const int lane = t & 63, wave = t >> 6;           // 8 waves
    const int l15 = lane & 15, quad = lane >> 4;

    const int qv = (Lq - q0) < 16 ? (Lq - q0) : 16;

    const bf16* Kbase = k + (size_t)b * Lk * ldkv + h * DK;
    const bf16* Vbase = v + (size_t)b * Lk * ldkv + h * DK;
    bf16* Qbase = q + (size_t)(b * Lq + q0) * ldq + h * DK;

    const int kmax = (MODE == 1) ? (q0 + 16 < Lk ? q0 + 16 : Lk) : Lk;
    const int ntile = (kmax + 63) >> 6;
    const int kpad = ntile << 6;
    const int nchunk = kpad >> 4;

    if (t < 128) {
        const int qr = t >> 3;
        const int qsrc = qr < qv ? qr : qv - 1;
        *(s8v*)&Qs[qr * 72 + (t & 7) * 8] =
            *(const s8v*)(Qbase + (size_t)qsrc * ldq + (t & 7) * 8);
    }
    __syncthreads();

    // ---- phase 1: S = QK^T / 8 (+ masks); 2-deep K-load pipeline ----
    {
        const s8v a0 = *(const s8v*)&Qs[l15 * 72 + quad * 8];
        const s8v a1 = *(const s8v*)&Qs[l15 * 72 + 32 + quad * 8];
        int c = wave;
        s8v b0, b1;
        if (c < nchunk) {
            int srow = c * 16 + l15; if (srow >= Lk) srow = Lk - 1;
            const bf16* kp = Kbase + (size_t)srow * ldkv + quad * 8;
            b0 = *(const s8v*)kp;
            b1 = *(const s8v*)(kp + 32);
        }
        while (c < nchunk) {
            const int cn = c + 8;
            s8v n0, n1;
            if (cn < nchunk) {
                int srow = cn * 16 + l15; if (srow >= Lk) srow = Lk - 1;
                const bf16* kp = Kbase + (size_t)srow * ldkv + quad * 8;
                n0 = *(const s8v*)kp;
                n1 = *(const s8v*)(kp + 32);
            }
            f4v acc = {0.f, 0.f, 0.f, 0.f};
            acc = __builtin_amdgcn_mfma_f32_16x16x32_bf16(a0, b0, acc, 0, 0, 0);
            acc = __builtin_amdgcn_mfma_f32_16x16x32_bf16(a1, b1, acc, 0, 0, 0);
            const int colg = c * 16 + l15;
            #pragma unroll
            for (int r = 0; r < 4; ++r) {
                const int qrow = quad * 4 + r;
                float s = acc[r] * 0.125f;
                if (colg >= Lk) s = -1e9f;
                if (MODE == 1 && colg > q0 + qrow) s = -1e9f;
                S[qrow * 516 + colg] = s;
            }
            b0 = n0; b1 = n1; c = cn;
        }
    }
    __syncthreads();

    // ---- phase 2+3: two rows per wave; lane = output dim ----
    #pragma unroll
    for (int rr = 0; rr < 2; ++rr) {
        const int row = wave + 8 * rr;
        float a = 0.f;
        float inv;
        if (MODE == 0) {
            // packed keys: 23-bit quantized score | 9-bit col; 0 for padded cols
            unsigned key[8];
            #pragma unroll
            for (int j = 0; j < 8; ++j) {
                const int col = lane + 64 * j;
                key[j] = (col < kpad)
                    ? ((f2ord(S[row * 516 + col]) & 0xFFFFFE00u) | (unsigned)col)
                    : 0u;
            }
            // row max (exp offset): one butterfly over per-lane max
            unsigned km = key[0];
            #pragma unroll
            for (int j = 1; j < 8; ++j) km = km > key[j] ? km : key[j];
            #pragma unroll
            for (int off = 1; off < 64; off <<= 1) {
                const unsigned o = __shfl_xor(km, off);
                km = km > o ? km : o;
            }
            const float mr = S[row * 516 + (int)(km & 511u)];

            // full-32-bit binary search: largest T with count(key >= T) >= 16.
            // Keys distinct (col bits) -> terminates with count exactly 16.
            unsigned T = 0u;
            for (int bbit = 31; bbit >= 0; --bbit) {
                const unsigned T2 = T | (1u << bbit);
                int c = 0;
                #pragma unroll
                for (int j = 0; j < 8; ++j)
                    c += (int)__popcll(__ballot(key[j] >= T2));
                if (c >= 16) {
                    T = T2;
                    if (c == 16) break;
                }
            }

            // single-class compaction: exactly the 16 keys >= T -> (col, e) in LDS
            int cnt = 0;
            #pragma unroll
            for (int j = 0; j < 8; ++j) {
                const bool s = key[j] >= T;
                const unsigned long long bal = __ballot(s);
                if (s) {
                    const int p = cnt + popc_lt(bal);
                    const int col = (int)(key[j] & 511u);
                    PC[row][p] = col;
                    PE[row][p] = expf(S[row * 516 + col] - mr);
                }
                cnt += (int)__popcll(bal);
            }
            // wave-private row: same-wave DS ops execute in order; no barrier needed

            float den = 0.f;
            #pragma unroll
            for (int it = 0; it < 16; ++it) {
                const int col = PC[row][it];      // broadcast
                const float e = PE[row][it];
                den += e;
                a += e * b2f(Vbase[(size_t)col * ldkv + lane]);
            }
            inv = 1.f / den;
        } else {
            float lv = -INFINITY;
            #pragma unroll
            for (int j = 0; j < 8; ++j) {
                const int col = lane + 64 * j;
                if (col < kpad) lv = fmaxf(lv, S[row * 516 + col]);
            }
            #pragma unroll
            for (int off = 1; off < 64; off <<= 1) lv = fmaxf(lv, __shfl_xor(lv, off));
            float part = 0.f;
            #pragma unroll
            for (int j = 0; j < 8; ++j) {
                const int col = lane + 64 * j;
                if (col < kpad) {
                    const float w = expf(S[row * 516 + col] - lv);
                    S[row * 516 + col] = w;
                    part += w;
                }
            }
            #pragma unroll
            for (int off = 1; off < 64; off <<= 1) part += __shfl_xor(part, off);
            inv = 1.f / part;
            const int kend = (MODE == 1) ? (q0 + row + 1 < kmax ? q0 + row + 1 : kmax) : kmax;
            #pragma unroll 4
            for (int k2 = 0; k2 < kend; ++k2)
                a += S[row * 516 + k2] * b2f(Vbase[(size_t)k2 * ldkv + lane]);
        }
        if (row < qv)
            Qbase[(size_t)row * ldq + lane] = __float2bfloat16(a * inv);
    }
}

// ---------------- layernorm over D=512, optional residual; in-place safe ----------------
__global__ __launch_bounds__(256) void ln_off_k(
    const bf16* __restrict__ X, const bf16* __restrict__ R,
    const void* __restrict__ gb, unsigned goff,
    bf16* __restrict__ Out, const int* __restrict__ flagp)
{
    __shared__ float red[4];
    const int f = *flagp;
    const int t = threadIdx.x;
    const size_t base = (size_t)blockIdx.x * DM;
    float v0 = b2f(X[base + t]), v1 = b2f(X[base + t + 256]);
    if (R) { v0 += b2f(R[base + t]); v1 += b2f(R[base + t + 256]); }
    const float mean = block_sum256(v0 + v1, red) * (1.f / 512.f);
    const float d0 = v0 - mean, d1 = v1 - mean;
    const float var = block_sum256(d0 * d0 + d1 * d1, red) * (1.f / 512.f);
    const float rstd = rsqrtf(var + 1e-5f);
    Out[base + t]       = __float2bfloat16(d0 * rstd * ldw(gb, goff + t, f)       + ldw(gb, goff + 512 + t, f));
    Out[base + t + 256] = __float2bfloat16(d1 * rstd * ldw(gb, goff + t + 256, f) + ldw(gb, goff + 768 + t, f));
}

// ---------------- conv distill helpers ----------------
// conv weights w[2][o][c][j] -> transposed GEMM layout wt[layer][o][j*512+c]
__global__ __launch_bounds__(256) void convw_k(const void* __restrict__ w,
                                               bf16* __restrict__ wt, int total,
                                               const int* __restrict__ flagp) {
    const int f = *flagp;
    int i = blockIdx.x * 256 + threadIdx.x;
    if (i >= total) return;
    const int layer = i / 786432, rem2 = i % 786432;
    const int o = rem2 / 1536, rem = rem2 % 1536;
    const int j = rem >> 9, c = rem & 511;
    wt[i] = __float2bfloat16(ldw(w, (unsigned)layer * 786432u + (unsigned)(o * 512 + c) * 3 + j, f));
}

__global__ __launch_bounds__(256) void convidx_k(int* __restrict__ idx, int Lc, int L, int total) {
    int i = blockIdx.x * 256 + threadIdx.x;
    if (i >= total) return;
    const int j = i / (16 * Lc), mrem = i % (16 * Lc);
    const int b = mrem / Lc, l = mrem % Lc;
    int src = l + j - 2;
    src %= L; if (src < 0) src += L;
    idx[i] = b * L + src;
}

__global__ __launch_bounds__(256) void bnstat1_k(const bf16* __restrict__ Y, float* __restrict__ part, int M) {
    const int t = threadIdx.x;
    float s0 = 0.f, q0 = 0.f, s1 = 0.f, q1 = 0.f;
    for (int r = blockIdx.x; r < M; r += gridDim.x) {
        const ushort2 u = *reinterpret_cast<const ushort2*>(Y + (size_t)r * DM + t * 2);
        const float a = u2f(u.x), c = u2f(u.y);
        s0 += a; q0 += a * a;
        s1 += c; q1 += c * c;
    }
    float* p = part + (size_t)blockIdx.x * 1024;
    p[2 * t] = s0; p[2 * t + 1] = s1;
    p[512 + 2 * t] = q0; p[512 + 2 * t + 1] = q1;
}

__global__ __launch_bounds__(256) void bnstat2_k(const float* __restrict__ part, float* __restrict__ stats,
                                                 int nchunk, int M) {
    const int ch = blockIdx.x * 256 + threadIdx.x;
    if (ch >= 512) return;
    float S = 0.f, Qs = 0.f;
    for (int c = 0; c < nchunk; ++c) { S += part[c * 1024 + ch]; Qs += part[c * 1024 + 512 + ch]; }
    const float mean = S / (float)M;
    const float var = Qs / (float)M - mean * mean;
    stats[ch] = mean;
    stats[512 + ch] = fmaxf(var, 0.f);
}

__global__ __launch_bounds__(256) void bnpool_k(
    const bf16* __restrict__ Yc, const float* __restrict__ stats,
    const void* __restrict__ g, const void* __restrict__ bb, unsigned off,
    bf16* __restrict__ Out, int Lc, int Lout, int total, const int* __restrict__ flagp)
{
    const int f = *flagp;
    int i = blockIdx.x * 256 + threadIdx.x;
    if (i >= total) return;
    const int ch = i & 511;
    const int lp = (i >> 9) % Lout;
    const int b = i / (512 * Lout);
    const float mean = stats[ch], var = stats[512 + ch];
    const float sc = ldw(g, off + ch, f) * rsqrtf(var + 1e-5f);
    const float sh = ldw(bb, off + ch, f) - mean * sc;
    float mx = -INFINITY;
    const int l0 = 2 * lp - 1;
    #pragma unroll
    for (int d = 0; d < 3; ++d) {
        const int l = l0 + d;
        if (l >= 0 && l < Lc) {
            float v = b2f(Yc[((size_t)b * Lc + l) * DM + ch]) * sc + sh;
            v = v > 0.f ? v : expm1f(v);  // ELU
            mx = fmaxf(mx, v);
        }
    }
    Out[((size_t)b * Lout + lp) * DM + ch] = __float2bfloat16(mx);
}

// ---------------- final projection to CO=7, dtype-matched store ----------------
__global__ __launch_bounds__(256) void fc_k(
    const bf16* __restrict__ Yn, const void* __restrict__ fcw, const void* __restrict__ fcb,
    void* __restrict__ out, int total, const int* __restrict__ flagp)
{
    const int f = *flagp;
    int i = blockIdx.x * 256 + threadIdx.x;
    if (i >= total) return;
    const int r = i / 7, co = i % 7;
    const bf16* yr = Yn + (size_t)r * DM;
    float acc = ldw(fcb, co, f);
    for (int d = 0; d < DM; ++d) acc += b2f(yr[d]) * ldw(fcw, d * 7 + co, f);
    if (f) ((bf16*)out)[i] = __float2bfloat16(acc);
    else   ((float*)out)[i] = acc;
}

// =============================================================================
extern "C" void kernel_launch(void* const* d_in, const int* in_sizes, int n_in,
                              void* d_out, int out_size, void* d_ws, size_t ws_size,
                              hipStream_t stream)
{
    const void* x_enc      = d_in[0];
    const void* x_mark_enc = d_in[1];
    const void* x_dec      = d_in[2];
    const void* x_mark_dec = d_in[3];
    const void* enc_vw = d_in[4];
    const void* enc_vb = d_in[5];
    const void* enc_mw = d_in[6];
    const void* enc_mb = d_in[7];
    const void* dec_vw = d_in[8];
    const void* dec_vb = d_in[9];
    const void* dec_mw = d_in[10];
    const void* dec_mb = d_in[11];
    const void* eW    = d_in[12];
    const void* ebi   = d_in[13];
    const void* effw1 = d_in[14];
    const void* effb1 = d_in[15];
    const void* effw2 = d_in[16];
    const void* effb2 = d_in[17];
    const void* eln1  = d_in[18];
    const void* eln2  = d_in[19];
    const void* cw    = d_in[20];
    const void* cb    = d_in[21];
    const void* cbn_g = d_in[22];
    const void* cbn_b = d_in[23];
    const void* enc_norm = d_in[24];
    const void* dsW   = d_in[25];
    const void* dsb   = d_in[26];
    const void* dcW   = d_in[27];
    const void* dcb   = d_in[28];
    const void* dffw1 = d_in[29];
    const void* dffb1 = d_in[30];
    const void* dffw2 = d_in[31];
    const void* dffb2 = d_in[32];
    const void* dln   = d_in[33];
    const void* dec_norm = d_in[34];
    const void* fcw   = d_in[35];
    const void* fcb   = d_in[36];

    // ---- workspace layout (~90 MiB; 111 MiB footprint ran clean in round 1) ----
    // X    [0, 8M)      : encoder acts; MEM + Yd in decoder phase
    // QKV  [8M, 40M)    : fused QKV / FFN hidden (aliased) / conv out / cross CQ+CKV
    // OUT  [40M, 48M)   : O-proj / FFN2 dest
    // WT   [48M, ~86.8M): ALL transposed weights (one-time prologue)
    // misc [88M, ~90M)  : IDX0/IDX1, PART, STATS, FLAG
    char* wsp = (char*)d_ws;
    bf16* X    = (bf16*)wsp;
    bf16* QKV  = (bf16*)(wsp + ((size_t)8 << 20));
    bf16* HID  = QKV;                                 // FFN hidden aliases dead QKV
    bf16* OUT  = (bf16*)(wsp + ((size_t)40 << 20));
    bf16* WT   = (bf16*)(wsp + ((size_t)48 << 20));
    int*   IDX0 = (int*)(wsp + ((size_t)88 << 20));   // 3*16*514 = 24672 ints
    int*   IDX1 = IDX0 + 24672;                       // 3*16*259 = 12432 ints
    float* PART = (float*)(wsp + ((size_t)89 << 20));
    float* STATS= (float*)(wsp + ((size_t)89 << 20) + (1 << 18));
    int*   FLAG = (int*)(wsp + ((size_t)89 << 20) + (1 << 18) + 4096);
    bf16* MEMb = X;                                               // [2080][512]
    bf16* Yd   = (bf16*)(wsp + (size_t)16 * 130 * 512 * 2);       // [4096][512]

    // transposed weight sub-arenas (element offsets)
    bf16* WTE  = WT;                    // enc QKVO: (i*4+q)*262144
    bf16* EW1T = WT + 3145728;          // + i*1048576
    bf16* EW2T = WT + 6291456;          // + i*1048576
    bf16* CWT  = WT + 9437184;          // + i*786432
    bf16* DSWt = WT + 11010048;         // + (i*4+q)*262144
    bf16* DCWt = WT + 13107200;
    bf16* DW1T = WT + 15204352;
    bf16* DW2T = WT + 17301504;

    auto cdiv = [](int a, int b) { return (a + b - 1) / b; };
    auto gemm = [&](const bf16* A, const bf16* Wt, const void* bias, unsigned boff,
                    bf16* C, int M, int N, int K, int lda, int ldc, bool relu) {
        dim3 g(N / 128, cdiv(M, 128));
        if (relu) mgemm_k<false, true><<<g, 256, 0, stream>>>(
            (const short*)A, nullptr, (const short*)Wt, bias, boff, C, M, N, K, lda, ldc, FLAG);
        else      mgemm_k<false, false><<<g, 256, 0, stream>>>(
            (const short*)A, nullptr, (const short*)Wt, bias, boff, C, M, N, K, lda, ldc, FLAG);
    };
    auto gemm64 = [&](const bf16* A, const bf16* Wt, const void* bias, unsigned boff,
                      bf16* C, int M, int N, int K, int lda, int ldc) {
        dim3 g(N / 64, cdiv(M, 128));
        mgemm64_k<false, false><<<g, 128, 0, stream>>>(
            (const short*)A, nullptr, (const short*)Wt, bias, boff, C, M, N, K, lda, ldc, FLAG);
    };
    auto transp = [&](const void* W, unsigned zstride, int nz, bf16* out, int K, int N) {
        transp_k<<<dim3(N / 32, K / 32, nz), 256, 0, stream>>>(W, 0u, zstride, out, K, N, FLAG);
    };

    // ---- prologue: sniff, all weight transposes, conv indices, embeddings ----
    sniff_k<<<1, 256, 0, stream>>>((const unsigned*)x_mark_enc, 16384, FLAG);
    transp(eW,    262144u, 12, WTE,  512, 512);
    transp(effw1, 1048576u, 3, EW1T, 512, 2048);
    transp(effw2, 1048576u, 3, EW2T, 2048, 512);
    convw_k<<<cdiv(1572864, 256), 256, 0, stream>>>(cw, CWT, 1572864, FLAG);
    transp(dsW,   262144u, 8, DSWt, 512, 512);
    transp(dcW,   262144u, 8, DCWt, 512, 512);
    transp(dffw1, 1048576u, 2, DW1T, 512, 2048);
    transp(dffw2, 1048576u, 2, DW2T, 2048, 512);
    convidx_k<<<cdiv(24672, 256), 256, 0, stream>>>(IDX0, 514, 512, 24672);
    convidx_k<<<cdiv(12432, 256), 256, 0, stream>>>(IDX1, 259, 257, 12432);
    embed_k<<<cdiv(16 * 512 * 512, 256), 256, 0, stream>>>(
        x_enc, enc_vw, enc_vb, x_mark_enc, enc_mw, enc_mb, X, 16 * 512, 7, 4, FLAG);

    // ---- encoder ----
    int L = 512;
    for (int i = 0; i < 3; ++i) {
        const int rows = 16 * L;
        const unsigned b0 = (unsigned)i * 4u * 512u;
        gemm(X, WTE + (size_t)i * 4 * 262144, ebi, b0, QKV, rows, 1536, 512, 512, 1536, false);
        fattn_k<0><<<dim3(cdiv(L, 16), 8, 16), 512, 0, stream>>>(
            QKV, QKV + 512, QKV + 1024, 1536, 1536, L, L);
        gemm64(QKV, WTE + (size_t)(i * 4 + 3) * 262144, ebi, b0 + 1536u, OUT, rows, 512, 512, 1536, 512);
        ln_off_k<<<rows, 256, 0, stream>>>(X, OUT, eln1, (unsigned)i * 1024u, X, FLAG);

        gemm(X, EW1T + (size_t)i * 1048576, effb1, (unsigned)i * 2048u, HID, rows, 2048, 512, 512, 2048, true);
        gemm64(HID, EW2T + (size_t)i * 1048576, effb2, (unsigned)i * 512u, OUT, rows, 512, 2048, 2048, 512);
        ln_off_k<<<rows, 256, 0, stream>>>(X, OUT, eln2, (unsigned)i * 1024u, X, FLAG);

        if (i < 2) {
            const int Lc = L + 2, Mc = 16 * Lc;
            const int* IDXi = (i == 0) ? IDX0 : IDX1;
            mgemm64_k<true, false><<<dim3(8, cdiv(Mc, 128)), 128, 0, stream>>>(
                (const short*)X, IDXi, (const short*)(CWT + (size_t)i * 786432),
                cb, (unsigned)i * 512u, QKV, Mc, 512, 1536, 512, 512, FLAG);
            bnstat1_k<<<32, 256, 0, stream>>>(QKV, PART, Mc);
            bnstat2_k<<<2, 256, 0, stream>>>(PART, STATS, 32, Mc);
            const int Lout = (L + 1) / 2 + 1;   // 514->257, 259->130
            const int tot = 16 * Lout * 512;
            bnpool_k<<<cdiv(tot, 256), 256, 0, stream>>>(
                QKV, STATS, cbn_g, cbn_b, (unsigned)i * 512u, X, Lc, Lout, tot, FLAG);
            L = Lout;
        }
    }
    const int Lm = L;  // 130
    ln_off_k<<<16 * Lm, 256, 0, stream>>>(X, nullptr, enc_norm, 0u, MEMb, FLAG);

    // ---- decoder embedding ----
    const int rowsD = 16 * 256;
    embed_k<<<cdiv(rowsD * 512, 256), 256, 0, stream>>>(
        x_dec, dec_vw, dec_vb, x_mark_dec, dec_mw, dec_mb, Yd, rowsD, 7, 4, FLAG);

    // ---- decoder ----
    bf16* CQ  = QKV;                       // [4096][512]
    bf16* CKV = QKV + (size_t)4096 * 512;  // [2080][1024]
    for (int i = 0; i < 2; ++i) {
        const unsigned b0 = (unsigned)i * 4u * 512u;
        // self-attention
        gemm(Yd, DSWt + (size_t)i * 4 * 262144, dsb, b0, QKV, rowsD, 1536, 512, 512, 1536, false);
        fattn_k<1><<<dim3(16, 8, 16), 512, 0, stream>>>(
            QKV, QKV + 512, QKV + 1024, 1536, 1536, 256, 256);
        gemm64(QKV, DSWt + (size_t)(i * 4 + 3) * 262144, dsb, b0 + 1536u, OUT, rowsD, 512, 512, 1536, 512);
        ln_off_k<<<rowsD, 256, 0, stream>>>(Yd, OUT, dln, (unsigned)(i * 3 + 0) * 1024u, Yd, FLAG);

        // cross-attention
        gemm64(Yd, DCWt + (size_t)i * 4 * 262144, dcb, b0, CQ, rowsD, 512, 512, 512, 512);
        gemm(MEMb, DCWt + (size_t)(i * 4 + 1) * 262144, dcb, b0 + 512u, CKV, 16 * Lm, 1024, 512, 512, 1024, false);
        fattn_k<2><<<dim3(16, 8, 16), 512, 0, stream>>>(
            CQ, CKV, CKV + 512, 512, 1024, 256, Lm);
        gemm64(CQ, DCWt + (size_t)(i * 4 + 3) * 262144, dcb, b0 + 1536u, OUT, rowsD, 512, 512, 512, 512);
        ln_off_k<<<rowsD, 256, 0, stream>>>(Yd, OUT, dln, (unsigned)(i * 3 + 1) * 1024u, Yd, FLAG);

        // FFN
        gemm(Yd, DW1T + (size_t)i * 1048576, dffb1, (unsigned)i * 2048u, HID, rowsD, 2048, 512, 512, 2048, true);
        gemm64(HID, DW2T + (size_t)i * 1048576, dffb2, (unsigned)i * 512u, OUT, rowsD, 512, 2048, 2048, 512);
        ln_off_k<<<rowsD, 256, 0, stream>>>(Yd, OUT, dln, (unsigned)(i * 3 + 2) * 1024u, Yd, FLAG);
    }

    ln_off_k<<<rowsD, 256, 0, stream>>>(Yd, nullptr, dec_norm, 0u, OUT, FLAG);
    fc_k<<<cdiv(rowsD * 7, 256), 256, 0, stream>>>(OUT, fcw, fcb, d_out, rowsD * 7, FLAG);
}

// Round 5
// 1547.700 us; speedup vs baseline: 1.2365x; 1.1159x over previous
//
#include <hip/hip_runtime.h>
#include <hip/hip_bf16.h>

// Informer forward, MI355X. Round 13: GEMM concurrency fix (the ~1.2ms GEMM chain).
//  - Analysis: GEMMs = 174 GF at ~145 TF (6% peak) dominate the 1727us wall. Old
//    mgemm64_k (128x64 tile, 128 thr) launches (N/64)x(M/128) <= 512 blocks for all
//    N=512 GEMMs (O/FFN2/conv/cross) -> 2 blocks x 2 waves = 1 wave/SIMD per CU;
//    every barrier+vmcnt drain idles the CU. Layer-2/3 + decoder mgemm grids
//    (136-528 blocks) similarly starved.
//  - Fix: mgemm64_k rebuilt as 64x64 tile, 256 thr (4 waves, each 32x32 = 2x2 frags,
//    IDENTICAL frag mapping + K order -> bit-identical numerics), grid (N/64)x(M/64):
//    2-4x blocks, 8KB LDS, >= 4 blocks/CU -> 16 waves/CU. All GEMMs routed through it
//    except encoder-L1 QKV + FFN1 (keep 128^2 mgemm_k at 3-4 blocks/CU).
//  - fattn untouched (round-12 state: 96.7us, occ 44%) for clean A/B.
// Retained: ballot radix-select top-16 fattn (512 thr), direct-global K frags,
// global_load_lds (width=16) staging, weight-transpose prologue, dtype sniffer.
// Round 12: passed, absmax 0.0117, 1727.1 us.
// B=16, LE=512, LD=256, D=512, H=8, dk=64, DFF=2048, NE=3, ND=2, TOPK=16.
// Encoder lengths: 512 -> conv(514)/pool -> 257 -> conv(259)/pool -> 130.

#define DM 512
#define DK 64

using bf16 = __hip_bfloat16;
typedef short s8v __attribute__((ext_vector_type(8)));
typedef float f4v __attribute__((ext_vector_type(4)));

__device__ inline float b2f(bf16 x) { return __bfloat162float(x); }
__device__ inline float u2f(unsigned short u) { return __uint_as_float((unsigned)u << 16); }

// flag f: 1 = raw inputs are bf16, 0 = raw inputs are fp32. idx in ELEMENTS.
__device__ inline float ldw(const void* p, unsigned i, int f) {
    return f ? b2f(((const bf16*)p)[i]) : ((const float*)p)[i];
}

// order-preserving float->u32 (monotonic)
__device__ inline unsigned f2ord(float s) {
    unsigned u = __float_as_uint(s);
    return u ^ ((unsigned)((int)u >> 31) | 0x80000000u);
}

// popcount of mask bits strictly below this lane
__device__ inline int popc_lt(unsigned long long m) {
    return (int)__builtin_amdgcn_mbcnt_hi((unsigned)(m >> 32),
            __builtin_amdgcn_mbcnt_lo((unsigned)m, 0u));
}

// async global->LDS, 16 B per lane; lds dst must be wave-uniform (lane i lands at dst+16*i)
__device__ inline void gl_lds16(const short* g, short* l) {
    __builtin_amdgcn_global_load_lds(
        (const __attribute__((address_space(1))) unsigned int*)g,
        (__attribute__((address_space(3))) unsigned int*)l,
        16, 0, 0);
}

// ---------------- dtype sniffer ----------------
__global__ __launch_bounds__(256) void sniff_k(const unsigned* __restrict__ x, int nwords,
                                               int* __restrict__ flag) {
    __shared__ int red[4];
    const int t = threadIdx.x;
    int c = 0;
    for (int i = t; i < nwords; i += 256) c += ((x[i] & 0x7F80u) == 0x3F80u) ? 1 : 0;
    #pragma unroll
    for (int o = 32; o > 0; o >>= 1) c += __shfl_down(c, o);
    __syncthreads();
    if ((t & 63) == 0) red[t >> 6] = c;
    __syncthreads();
    if (t == 0) flag[0] = (red[0] + red[1] + red[2] + red[3] > nwords / 20) ? 1 : 0;
}

// ---------------- reductions (blockDim == 256) ----------------
__device__ inline float block_sum256(float v, float* red) {
    #pragma unroll
    for (int o = 32; o > 0; o >>= 1) v += __shfl_down(v, o);
    __syncthreads();
    if ((threadIdx.x & 63) == 0) red[threadIdx.x >> 6] = v;
    __syncthreads();
    return red[0] + red[1] + red[2] + red[3];
}

// ---------------- embedding ----------------
__global__ __launch_bounds__(256) void embed_k(
    const void* __restrict__ xv, const void* __restrict__ vw, const void* __restrict__ vb,
    const void* __restrict__ xm, const void* __restrict__ mw, const void* __restrict__ mb,
    bf16* __restrict__ Out, int rows, int Cv, int Cm, const int* __restrict__ flagp)
{
    const int f = *flagp;
    int i = blockIdx.x * 256 + threadIdx.x;
    if (i >= rows * DM) return;
    const int r = i >> 9, d = i & 511;
    float acc = ldw(vb, d, f) + ldw(mb, d, f);
    for (int c = 0; c < Cv; ++c) acc += ldw(xv, r * Cv + c, f) * ldw(vw, c * DM + d, f);
    for (int c = 0; c < Cm; ++c) acc += ldw(xm, r * Cm + c, f) * ldw(mw, c * DM + d, f);
    Out[i] = __float2bfloat16(acc);
}

// ---------------- weight transpose: raw [K][N] -> bf16 [N][K]; z batches sub-mats ----------------
__global__ __launch_bounds__(256) void transp_k(
    const void* __restrict__ W, unsigned off, unsigned zstride, bf16* __restrict__ out,
    int K, int N, const int* __restrict__ flagp)
{
    __shared__ float tile[32][33];
    const int f = *flagp;
    const unsigned zo = blockIdx.z * zstride;
    const int t = threadIdx.x;
    const int tx = t & 31, ty = t >> 5;               // 32 x 8
    const int n0 = blockIdx.x * 32, k0 = blockIdx.y * 32;
    #pragma unroll
    for (int i = 0; i < 4; ++i)
        tile[ty + 8 * i][tx] = ldw(W, off + zo + (unsigned)(k0 + ty + 8 * i) * N + n0 + tx, f);
    __syncthreads();
    #pragma unroll
    for (int i = 0; i < 4; ++i)
        out[(size_t)zo + (size_t)(n0 + ty + 8 * i) * K + k0 + tx] = __float2bfloat16(tile[tx][ty + 8 * i]);
}

// ---------------- MFMA GEMM 128x128 (256 thr): C = A[M,K]@Wt[N,K]^T + bias ----------------
// Staging via global_load_lds (16 B/lane), unpadded [row][32]-short LDS tiles.
// Used only for large-grid GEMMs (encoder L1 QKV / FFN1: >= 768 blocks).
template<bool G3, bool RELU>
__global__ __launch_bounds__(256) void mgemm_k(
    const short* __restrict__ A, const int* __restrict__ ridx,
    const short* __restrict__ Wt,
    const void* __restrict__ bias, unsigned boff0,
    bf16* __restrict__ C, int M, int N, int K, int lda, int ldc,
    const int* __restrict__ flagp)
{
    __shared__ short As[128 * 32];
    __shared__ short Ws[128 * 32];
    const int t = threadIdx.x;
    const int bm = blockIdx.y * 128, bn = blockIdx.x * 128;
    const int lane = t & 63, wave = t >> 6;
    const int mbase = (wave >> 1) * 64, nbase = (wave & 1) * 64;
    const int l15 = lane & 15, quad = lane >> 4;
    const int lrow = lane >> 2, lk = (lane & 3) * 8;

    f4v acc[4][4] = {};

    for (int k0 = 0; k0 < K; k0 += 32) {
        __syncthreads();
        #pragma unroll
        for (int j = 0; j < 2; ++j) {
            const int rb = wave * 32 + j * 16;
            const int row = bm + rb + lrow;
            const int rowc = row < M ? row : M - 1;
            const short* g;
            if (G3) {
                const int r = ridx[(k0 >> 9) * M + rowc];
                g = A + (size_t)r * lda + (k0 & 511) + lk;
            } else {
                g = A + (size_t)rowc * lda + k0 + lk;
            }
            gl_lds16(g, &As[rb * 32]);
        }
        #pragma unroll
        for (int j = 0; j < 2; ++j) {
            const int nb = wave * 32 + j * 16;
            gl_lds16(Wt + (size_t)(bn + nb + lrow) * K + k0 + lk, &Ws[nb * 32]);
        }
        __syncthreads();
        s8v af[4], bfv[4];
        #pragma unroll
        for (int i = 0; i < 4; ++i) {
            af[i]  = *(const s8v*)&As[(mbase + i * 16 + l15) * 32 + quad * 8];
            bfv[i] = *(const s8v*)&Ws[(nbase + i * 16 + l15) * 32 + quad * 8];
        }
        #pragma unroll
        for (int mi = 0; mi < 4; ++mi)
            #pragma unroll
            for (int ni = 0; ni < 4; ++ni)
                acc[mi][ni] = __builtin_amdgcn_mfma_f32_16x16x32_bf16(
                    af[mi], bfv[ni], acc[mi][ni], 0, 0, 0);
    }

    const int f = *flagp;
    float bv[4];
    #pragma unroll
    for (int ni = 0; ni < 4; ++ni)
        bv[ni] = ldw(bias, boff0 + (unsigned)(bn + nbase + ni * 16 + l15), f);

    #pragma unroll
    for (int mi = 0; mi < 4; ++mi) {
        #pragma unroll
        for (int r = 0; r < 4; ++r) {
            const int row = bm + mbase + mi * 16 + quad * 4 + r;
            if (row < M) {
                #pragma unroll
                for (int ni = 0; ni < 4; ++ni) {
                    float o = acc[mi][ni][r] + bv[ni];
                    if (RELU) o = fmaxf(o, 0.f);
                    C[(size_t)row * ldc + bn + nbase + ni * 16 + l15] = __float2bfloat16(o);
                }
            }
        }
    }
}

// ---------------- MFMA GEMM 64x64 (256 thr, 4 waves x 32x32): concurrency-first ----------------
// grid (N/64, cdiv(M,64)): 2-4x the blocks of the old 128x64/128-thr version ->
// >= 4 blocks/CU (8 KB LDS), 16 waves/CU. Same frag mapping / K order as mgemm_k.
template<bool G3, bool RELU>
__global__ __launch_bounds__(256) void mgemm64_k(
    const short* __restrict__ A, const int* __restrict__ ridx,
    const short* __restrict__ Wt,
    const void* __restrict__ bias, unsigned boff0,
    bf16* __restrict__ C, int M, int N, int K, int lda, int ldc,
    const int* __restrict__ flagp)
{
    __shared__ short As[64 * 32];
    __shared__ short Ws[64 * 32];
    const int t = threadIdx.x;
    const int bm = blockIdx.y * 64, bn = blockIdx.x * 64;
    const int lane = t & 63, wave = t >> 6;
    const int mbase = (wave >> 1) * 32, nbase = (wave & 1) * 32;
    const int l15 = lane & 15, quad = lane >> 4;
    const int lrow = lane >> 2, lk = (lane & 3) * 8;

    f4v acc[2][2] = {};

    for (int k0 = 0; k0 < K; k0 += 32) {
        __syncthreads();
        {   // A chunk: 16 rows per wave (4 waves cover 64)
            const int rb = wave * 16;
            const int row = bm + rb + lrow;
            const int rowc = row < M ? row : M - 1;
            const short* g;
            if (G3) {
                const int r = ridx[(k0 >> 9) * M + rowc];
                g = A + (size_t)r * lda + (k0 & 511) + lk;
            } else {
                g = A + (size_t)rowc * lda + k0 + lk;
            }
            gl_lds16(g, &As[rb * 32]);
        }
        {   // B chunk: 16 rows per wave
            const int nb = wave * 16;
            gl_lds16(Wt + (size_t)(bn + nb + lrow) * K + k0 + lk, &Ws[nb * 32]);
        }
        __syncthreads();
        s8v af[2], bfv[2];
        #pragma unroll
        for (int i = 0; i < 2; ++i) {
            af[i]  = *(const s8v*)&As[(mbase + i * 16 + l15) * 32 + quad * 8];
            bfv[i] = *(const s8v*)&Ws[(nbase + i * 16 + l15) * 32 + quad * 8];
        }
        #pragma unroll
        for (int mi = 0; mi < 2; ++mi)
            #pragma unroll
            for (int ni = 0; ni < 2; ++ni)
                acc[mi][ni] = __builtin_amdgcn_mfma_f32_16x16x32_bf16(
                    af[mi], bfv[ni], acc[mi][ni], 0, 0, 0);
    }

    const int f = *flagp;
    float bv[2];
    #pragma unroll
    for (int ni = 0; ni < 2; ++ni)
        bv[ni] = ldw(bias, boff0 + (unsigned)(bn + nbase + ni * 16 + l15), f);

    #pragma unroll
    for (int mi = 0; mi < 2; ++mi) {
        #pragma unroll
        for (int r = 0; r < 4; ++r) {
            const int row = bm + mbase + mi * 16 + quad * 4 + r;
            if (row < M) {
                #pragma unroll
                for (int ni = 0; ni < 2; ++ni) {
                    float o = acc[mi][ni][r] + bv[ni];
                    if (RELU) o = fmaxf(o, 0.f);
                    C[(size_t)row * ldc + bn + nbase + ni * 16 + l15] = __float2bfloat16(o);
                }
            }
        }
    }
}

// ---------------- fused tile attention (strided q/k/v), 512 threads ----------------
// MODE 0: ProbSparse top-16. MODE 1: causal. MODE 2: plain cross.
// 8 waves: phase 1 = MFMA QK^T, direct-global K frags, 2-deep load pipeline;
// phase 2+3 = 2 rows per wave (row = wave + 8*rr), lane = head dim.
// MODE 0 selection: full-32-bit ballot radix-select (keys distinct -> exact count 16).
template<int MODE>
__global__ __launch_bounds__(512, 8) void fattn_k(
    bf16* __restrict__ q, const bf16* __restrict__ k, const bf16* __restrict__ v,
    int ldq, int ldkv, int Lq, int Lk)
{
    __shared__ short Qs[16 * 72];
    __shared__ float S[16 * 516];
    __shared__ int   PC[16][16];
    __shared__ float PE[16][16];

    const int t = threadIdx.x;
    const int q0 = blockIdx.x * 16, h = blockIdx.y, b = blockIdx.z;
    const int lane = t & 63, wave = t >> 6;           // 8 waves
    const int l15 = lane & 15, quad = lane >> 4;

    const int qv = (Lq - q0) < 16 ? (Lq - q0) : 16;

    const bf16* Kbase = k + (size_t)b * Lk * ldkv + h * DK;
    const bf16* Vbase = v + (size_t)b * Lk * ldkv + h * DK;
    bf16* Qbase = q + (size_t)(b * Lq + q0) * ldq + h * DK;

    const int kmax = (MODE == 1) ? (q0 + 16 < Lk ? q0 + 16 : Lk) : Lk;
    const int ntile = (kmax + 63) >> 6;
    const int kpad = ntile << 6;
    const int nchunk = kpad >> 4;

    if (t < 128) {
        const int qr = t >> 3;
        const int qsrc = qr < qv ? qr : qv - 1;
        *(s8v*)&Qs[qr * 72 + (t & 7) * 8] =
            *(const s8v*)(Qbase + (size_t)qsrc * ldq + (t & 7) * 8);
    }
    __syncthreads();

    // ---- phase 1: S = QK^T / 8 (+ masks); 2-deep K-load pipeline ----
    {
        const s8v a0 = *(const s8v*)&Qs[l15 * 72 + quad * 8];
        const s8v a1 = *(const s8v*)&Qs[l15 * 72 + 32 + quad * 8];
        int c = wave;
        s8v b0, b1;
        if (c < nchunk) {
            int srow = c * 16 + l15; if (srow >= Lk) srow = Lk - 1;
            const bf16* kp = Kbase + (size_t)srow * ldkv + quad * 8;
            b0 = *(const s8v*)kp;
            b1 = *(const s8v*)(kp + 32);
        }
        while (c < nchunk) {
            const int cn = c + 8;
            s8v n0, n1;
            if (cn < nchunk) {
                int srow = cn * 16 + l15; if (srow >= Lk) srow = Lk - 1;
                const bf16* kp = Kbase + (size_t)srow * ldkv + quad * 8;
                n0 = *(const s8v*)kp;
                n1 = *(const s8v*)(kp + 32);
            }
            f4v acc = {0.f, 0.f, 0.f, 0.f};
            acc = __builtin_amdgcn_mfma_f32_16x16x32_bf16(a0, b0, acc, 0, 0, 0);
            acc = __builtin_amdgcn_mfma_f32_16x16x32_bf16(a1, b1, acc, 0, 0, 0);
            const int colg = c * 16 + l15;
            #pragma unroll
            for (int r = 0; r < 4; ++r) {
                const int qrow = quad * 4 + r;
                float s = acc[r] * 0.125f;
                if (colg >= Lk) s = -1e9f;
                if (MODE == 1 && colg > q0 + qrow) s = -1e9f;
                S[qrow * 516 + colg] = s;
            }
            b0 = n0; b1 = n1; c = cn;
        }
    }
    __syncthreads();

    // ---- phase 2+3: two rows per wave; lane = output dim ----
    #pragma unroll
    for (int rr = 0; rr < 2; ++rr) {
        const int row = wave + 8 * rr;
        float a = 0.f;
        float inv;
        if (MODE == 0) {
            // packed keys: 23-bit quantized score | 9-bit col; 0 for padded cols
            unsigned key[8];
            #pragma unroll
            for (int j = 0; j < 8; ++j) {
                const int col = lane + 64 * j;
                key[j] = (col < kpad)
                    ? ((f2ord(S[row * 516 + col]) & 0xFFFFFE00u) | (unsigned)col)
                    : 0u;
            }
            // row max (exp offset): one butterfly over per-lane max
            unsigned km = key[0];
            #pragma unroll
            for (int j = 1; j < 8; ++j) km = km > key[j] ? km : key[j];
            #pragma unroll
            for (int off = 1; off < 64; off <<= 1) {
                const unsigned o = __shfl_xor(km, off);
                km = km > o ? km : o;
            }
            const float mr = S[row * 516 + (int)(km & 511u)];

            // full-32-bit binary search: largest T with count(key >= T) >= 16.
            // Keys distinct (col bits) -> terminates with count exactly 16.
            unsigned T = 0u;
            for (int bbit = 31; bbit >= 0; --bbit) {
                const unsigned T2 = T | (1u << bbit);
                int c = 0;
                #pragma unroll
                for (int j = 0; j < 8; ++j)
                    c += (int)__popcll(__ballot(key[j] >= T2));
                if (c >= 16) {
                    T = T2;
                    if (c == 16) break;
                }
            }

            // single-class compaction: exactly the 16 keys >= T -> (col, e) in LDS
            int cnt = 0;
            #pragma unroll
            for (int j = 0; j < 8; ++j) {
                const bool s = key[j] >= T;
                const unsigned long long bal = __ballot(s);
                if (s) {
                    const int p = cnt + popc_lt(bal);
                    const int col = (int)(key[j] & 511u);
                    PC[row][p] = col;
                    PE[row][p] = expf(S[row * 516 + col] - mr);
                }
                cnt += (int)__popcll(bal);
            }
            // wave-private row: same-wave DS ops execute in order; no barrier needed

            float den = 0.f;
            #pragma unroll
            for (int it = 0; it < 16; ++it) {
                const int col = PC[row][it];      // broadcast
                const float e = PE[row][it];
                den += e;
                a += e * b2f(Vbase[(size_t)col * ldkv + lane]);
            }
            inv = 1.f / den;
        } else {
            float lv = -INFINITY;
            #pragma unroll
            for (int j = 0; j < 8; ++j) {
                const int col = lane + 64 * j;
                if (col < kpad) lv = fmaxf(lv, S[row * 516 + col]);
            }
            #pragma unroll
            for (int off = 1; off < 64; off <<= 1) lv = fmaxf(lv, __shfl_xor(lv, off));
            float part = 0.f;
            #pragma unroll
            for (int j = 0; j < 8; ++j) {
                const int col = lane + 64 * j;
                if (col < kpad) {
                    const float w = expf(S[row * 516 + col] - lv);
                    S[row * 516 + col] = w;
                    part += w;
                }
            }
            #pragma unroll
            for (int off = 1; off < 64; off <<= 1) part += __shfl_xor(part, off);
            inv = 1.f / part;
            const int kend = (MODE == 1) ? (q0 + row + 1 < kmax ? q0 + row + 1 : kmax) : kmax;
            #pragma unroll 4
            for (int k2 = 0; k2 < kend; ++k2)
                a += S[row * 516 + k2] * b2f(Vbase[(size_t)k2 * ldkv + lane]);
        }
        if (row < qv)
            Qbase[(size_t)row * ldq + lane] = __float2bfloat16(a * inv);
    }
}

// ---------------- layernorm over D=512, optional residual; in-place safe ----------------
__global__ __launch_bounds__(256) void ln_off_k(
    const bf16* __restrict__ X, const bf16* __restrict__ R,
    const void* __restrict__ gb, unsigned goff,
    bf16* __restrict__ Out, const int* __restrict__ flagp)
{
    __shared__ float red[4];
    const int f = *flagp;
    const int t = threadIdx.x;
    const size_t base = (size_t)blockIdx.x * DM;
    float v0 = b2f(X[base + t]), v1 = b2f(X[base + t + 256]);
    if (R) { v0 += b2f(R[base + t]); v1 += b2f(R[base + t + 256]); }
    const float mean = block_sum256(v0 + v1, red) * (1.f / 512.f);
    const float d0 = v0 - mean, d1 = v1 - mean;
    const float var = block_sum256(d0 * d0 + d1 * d1, red) * (1.f / 512.f);
    const float rstd = rsqrtf(var + 1e-5f);
    Out[base + t]       = __float2bfloat16(d0 * rstd * ldw(gb, goff + t, f)       + ldw(gb, goff + 512 + t, f));
    Out[base + t + 256] = __float2bfloat16(d1 * rstd * ldw(gb, goff + t + 256, f) + ldw(gb, goff + 768 + t, f));
}

// ---------------- conv distill helpers ----------------
// conv weights w[2][o][c][j] -> transposed GEMM layout wt[layer][o][j*512+c]
__global__ __launch_bounds__(256) void convw_k(const void* __restrict__ w,
                                               bf16* __restrict__ wt, int total,
                                               const int* __restrict__ flagp) {
    const int f = *flagp;
    int i = blockIdx.x * 256 + threadIdx.x;
    if (i >= total) return;
    const int layer = i / 786432, rem2 = i % 786432;
    const int o = rem2 / 1536, rem = rem2 % 1536;
    const int j = rem >> 9, c = rem & 511;
    wt[i] = __float2bfloat16(ldw(w, (unsigned)layer * 786432u + (unsigned)(o * 512 + c) * 3 + j, f));
}

__global__ __launch_bounds__(256) void convidx_k(int* __restrict__ idx, int Lc, int L, int total) {
    int i = blockIdx.x * 256 + threadIdx.x;
    if (i >= total) return;
    const int j = i / (16 * Lc), mrem = i % (16 * Lc);
    const int b = mrem / Lc, l = mrem % Lc;
    int src = l + j - 2;
    src %= L; if (src < 0) src += L;
    idx[i] = b * L + src;
}

__global__ __launch_bounds__(256) void bnstat1_k(const bf16* __restrict__ Y, float* __restrict__ part, int M) {
    const int t = threadIdx.x;
    float s0 = 0.f, q0 = 0.f, s1 = 0.f, q1 = 0.f;
    for (int r = blockIdx.x; r < M; r += gridDim.x) {
        const ushort2 u = *reinterpret_cast<const ushort2*>(Y + (size_t)r * DM + t * 2);
        const float a = u2f(u.x), c = u2f(u.y);
        s0 += a; q0 += a * a;
        s1 += c; q1 += c * c;
    }
    float* p = part + (size_t)blockIdx.x * 1024;
    p[2 * t] = s0; p[2 * t + 1] = s1;
    p[512 + 2 * t] = q0; p[512 + 2 * t + 1] = q1;
}

__global__ __launch_bounds__(256) void bnstat2_k(const float* __restrict__ part, float* __restrict__ stats,
                                                 int nchunk, int M) {
    const int ch = blockIdx.x * 256 + threadIdx.x;
    if (ch >= 512) return;
    float S = 0.f, Qs = 0.f;
    for (int c = 0; c < nchunk; ++c) { S += part[c * 1024 + ch]; Qs += part[c * 1024 + 512 + ch]; }
    const float mean = S / (float)M;
    const float var = Qs / (float)M - mean * mean;
    stats[ch] = mean;
    stats[512 + ch] = fmaxf(var, 0.f);
}

__global__ __launch_bounds__(256) void bnpool_k(
    const bf16* __restrict__ Yc, const float* __restrict__ stats,
    const void* __restrict__ g, const void* __restrict__ bb, unsigned off,
    bf16* __restrict__ Out, int Lc, int Lout, int total, const int* __restrict__ flagp)
{
    const int f = *flagp;
    int i = blockIdx.x * 256 + threadIdx.x;
    if (i >= total) return;
    const int ch = i & 511;
    const int lp = (i >> 9) % Lout;
    const int b = i / (512 * Lout);
    const float mean = stats[ch], var = stats[512 + ch];
    const float sc = ldw(g, off + ch, f) * rsqrtf(var + 1e-5f);
    const float sh = ldw(bb, off + ch, f) - mean * sc;
    float mx = -INFINITY;
    const int l0 = 2 * lp - 1;
    #pragma unroll
    for (int d = 0; d < 3; ++d) {
        const int l = l0 + d;
        if (l >= 0 && l < Lc) {
            float v = b2f(Yc[((size_t)b * Lc + l) * DM + ch]) * sc + sh;
            v = v > 0.f ? v : expm1f(v);  // ELU
            mx = fmaxf(mx, v);
        }
    }
    Out[((size_t)b * Lout + lp) * DM + ch] = __float2bfloat16(mx);
}

// ---------------- final projection to CO=7, dtype-matched store ----------------
__global__ __launch_bounds__(256) void fc_k(
    const bf16* __restrict__ Yn, const void* __restrict__ fcw, const void* __restrict__ fcb,
    void* __restrict__ out, int total, const int* __restrict__ flagp)
{
    const int f = *flagp;
    int i = blockIdx.x * 256 + threadIdx.x;
    if (i >= total) return;
    const int r = i / 7, co = i % 7;
    const bf16* yr = Yn + (size_t)r * DM;
    float acc = ldw(fcb, co, f);
    for (int d = 0; d < DM; ++d) acc += b2f(yr[d]) * ldw(fcw, d * 7 + co, f);
    if (f) ((bf16*)out)[i] = __float2bfloat16(acc);
    else   ((float*)out)[i] = acc;
}

// =============================================================================
extern "C" void kernel_launch(void* const* d_in, const int* in_sizes, int n_in,
                              void* d_out, int out_size, void* d_ws, size_t ws_size,
                              hipStream_t stream)
{
    const void* x_enc      = d_in[0];
    const void* x_mark_enc = d_in[1];
    const void* x_dec      = d_in[2];
    const void* x_mark_dec = d_in[3];
    const void* enc_vw = d_in[4];
    const void* enc_vb = d_in[5];
    const void* enc_mw = d_in[6];
    const void* enc_mb = d_in[7];
    const void* dec_vw = d_in[8];
    const void* dec_vb = d_in[9];
    const void* dec_mw = d_in[10];
    const void* dec_mb = d_in[11];
    const void* eW    = d_in[12];
    const void* ebi   = d_in[13];
    const void* effw1 = d_in[14];
    const void* effb1 = d_in[15];
    const void* effw2 = d_in[16];
    const void* effb2 = d_in[17];
    const void* eln1  = d_in[18];
    const void* eln2  = d_in[19];
    const void* cw    = d_in[20];
    const void* cb    = d_in[21];
    const void* cbn_g = d_in[22];
    const void* cbn_b = d_in[23];
    const void* enc_norm = d_in[24];
    const void* dsW   = d_in[25];
    const void* dsb   = d_in[26];
    const void* dcW   = d_in[27];
    const void* dcb   = d_in[28];
    const void* dffw1 = d_in[29];
    const void* dffb1 = d_in[30];
    const void* dffw2 = d_in[31];
    const void* dffb2 = d_in[32];
    const void* dln   = d_in[33];
    const void* dec_norm = d_in[34];
    const void* fcw   = d_in[35];
    const void* fcb   = d_in[36];

    // ---- workspace layout (~90 MiB; 111 MiB footprint ran clean in round 1) ----
    // X    [0, 8M)      : encoder acts; MEM + Yd in decoder phase
    // QKV  [8M, 40M)    : fused QKV / FFN hidden (aliased) / conv out / cross CQ+CKV
    // OUT  [40M, 48M)   : O-proj / FFN2 dest
    // WT   [48M, ~86.8M): ALL transposed weights (one-time prologue)
    // misc [88M, ~90M)  : IDX0/IDX1, PART, STATS, FLAG
    char* wsp = (char*)d_ws;
    bf16* X    = (bf16*)wsp;
    bf16* QKV  = (bf16*)(wsp + ((size_t)8 << 20));
    bf16* HID  = QKV;                                 // FFN hidden aliases dead QKV
    bf16* OUT  = (bf16*)(wsp + ((size_t)40 << 20));
    bf16* WT   = (bf16*)(wsp + ((size_t)48 << 20));
    int*   IDX0 = (int*)(wsp + ((size_t)88 << 20));   // 3*16*514 = 24672 ints
    int*   IDX1 = IDX0 + 24672;                       // 3*16*259 = 12432 ints
    float* PART = (float*)(wsp + ((size_t)89 << 20));
    float* STATS= (float*)(wsp + ((size_t)89 << 20) + (1 << 18));
    int*   FLAG = (int*)(wsp + ((size_t)89 << 20) + (1 << 18) + 4096);
    bf16* MEMb = X;                                               // [2080][512]
    bf16* Yd   = (bf16*)(wsp + (size_t)16 * 130 * 512 * 2);       // [4096][512]

    // transposed weight sub-arenas (element offsets)
    bf16* WTE  = WT;                    // enc QKVO: (i*4+q)*262144
    bf16* EW1T = WT + 3145728;          // + i*1048576
    bf16* EW2T = WT + 6291456;          // + i*1048576
    bf16* CWT  = WT + 9437184;          // + i*786432
    bf16* DSWt = WT + 11010048;         // + (i*4+q)*262144
    bf16* DCWt = WT + 13107200;
    bf16* DW1T = WT + 15204352;
    bf16* DW2T = WT + 17301504;

    auto cdiv = [](int a, int b) { return (a + b - 1) / b; };
    auto gemm = [&](const bf16* A, const bf16* Wt, const void* bias, unsigned boff,
                    bf16* C, int M, int N, int K, int lda, int ldc, bool relu) {
        dim3 g(N / 128, cdiv(M, 128));
        if (relu) mgemm_k<false, true><<<g, 256, 0, stream>>>(
            (const short*)A, nullptr, (const short*)Wt, bias, boff, C, M, N, K, lda, ldc, FLAG);
        else      mgemm_k<false, false><<<g, 256, 0, stream>>>(
            (const short*)A, nullptr, (const short*)Wt, bias, boff, C, M, N, K, lda, ldc, FLAG);
    };
    auto gemm64 = [&](const bf16* A, const bf16* Wt, const void* bias, unsigned boff,
                      bf16* C, int M, int N, int K, int lda, int ldc, bool relu) {
        dim3 g(N / 64, cdiv(M, 64));
        if (relu) mgemm64_k<false, true><<<g, 256, 0, stream>>>(
            (const short*)A, nullptr, (const short*)Wt, bias, boff, C, M, N, K, lda, ldc, FLAG);
        else      mgemm64_k<false, false><<<g, 256, 0, stream>>>(
            (const short*)A, nullptr, (const short*)Wt, bias, boff, C, M, N, K, lda, ldc, FLAG);
    };
    auto transp = [&](const void* W, unsigned zstride, int nz, bf16* out, int K, int N) {
        transp_k<<<dim3(N / 32, K / 32, nz), 256, 0, stream>>>(W, 0u, zstride, out, K, N, FLAG);
    };

    // ---- prologue: sniff, all weight transposes, conv indices, embeddings ----
    sniff_k<<<1, 256, 0, stream>>>((const unsigned*)x_mark_enc, 16384, FLAG);
    transp(eW,    262144u, 12, WTE,  512, 512);
    transp(effw1, 1048576u, 3, EW1T, 512, 2048);
    transp(effw2, 1048576u, 3, EW2T, 2048, 512);
    convw_k<<<cdiv(1572864, 256), 256, 0, stream>>>(cw, CWT, 1572864, FLAG);
    transp(dsW,   262144u, 8, DSWt, 512, 512);
    transp(dcW,   262144u, 8, DCWt, 512, 512);
    transp(dffw1, 1048576u, 2, DW1T, 512, 2048);
    transp(dffw2, 1048576u, 2, DW2T, 2048, 512);
    convidx_k<<<cdiv(24672, 256), 256, 0, stream>>>(IDX0, 514, 512, 24672);
    convidx_k<<<cdiv(12432, 256), 256, 0, stream>>>(IDX1, 259, 257, 12432);
    embed_k<<<cdiv(16 * 512 * 512, 256), 256, 0, stream>>>(
        x_enc, enc_vw, enc_vb, x_mark_enc, enc_mw, enc_mb, X, 16 * 512, 7, 4, FLAG);

    // ---- encoder ----
    int L = 512;
    for (int i = 0; i < 3; ++i) {
        const int rows = 16 * L;
        const unsigned b0 = (unsigned)i * 4u * 512u;
        // QKV: big grid only at L=512 -> mgemm; else 64x64 for concurrency
        if (i == 0) gemm(X, WTE + (size_t)i * 4 * 262144, ebi, b0, QKV, rows, 1536, 512, 512, 1536, false);
        else      gemm64(X, WTE + (size_t)i * 4 * 262144, ebi, b0, QKV, rows, 1536, 512, 512, 1536, false);
        fattn_k<0><<<dim3(cdiv(L, 16), 8, 16), 512, 0, stream>>>(
            QKV, QKV + 512, QKV + 1024, 1536, 1536, L, L);
        gemm64(QKV, WTE + (size_t)(i * 4 + 3) * 262144, ebi, b0 + 1536u, OUT, rows, 512, 512, 1536, 512, false);
        ln_off_k<<<rows, 256, 0, stream>>>(X, OUT, eln1, (unsigned)i * 1024u, X, FLAG);

        if (i == 0) gemm(X, EW1T + (size_t)i * 1048576, effb1, (unsigned)i * 2048u, HID, rows, 2048, 512, 512, 2048, true);
        else      gemm64(X, EW1T + (size_t)i * 1048576, effb1, (unsigned)i * 2048u, HID, rows, 2048, 512, 512, 2048, true);
        gemm64(HID, EW2T + (size_t)i * 1048576, effb2, (unsigned)i * 512u, OUT, rows, 512, 2048, 2048, 512, false);
        ln_off_k<<<rows, 256, 0, stream>>>(X, OUT, eln2, (unsigned)i * 1024u, X, FLAG);

        if (i < 2) {
            const int Lc = L + 2, Mc = 16 * Lc;
            const int* IDXi = (i == 0) ? IDX0 : IDX1;
            mgemm64_k<true, false><<<dim3(8, cdiv(Mc, 64)), 256, 0, stream>>>(
                (const short*)X, IDXi, (const short*)(CWT + (size_t)i * 786432),
                cb, (unsigned)i * 512u, QKV, Mc, 512, 1536, 512, 512, FLAG);
            bnstat1_k<<<32, 256, 0, stream>>>(QKV, PART, Mc);
            bnstat2_k<<<2, 256, 0, stream>>>(PART, STATS, 32, Mc);
            const int Lout = (L + 1) / 2 + 1;   // 514->257, 259->130
            const int tot = 16 * Lout * 512;
            bnpool_k<<<cdiv(tot, 256), 256, 0, stream>>>(
                QKV, STATS, cbn_g, cbn_b, (unsigned)i * 512u, X, Lc, Lout, tot, FLAG);
            L = Lout;
        }
    }
    const int Lm = L;  // 130
    ln_off_k<<<16 * Lm, 256, 0, stream>>>(X, nullptr, enc_norm, 0u, MEMb, FLAG);

    // ---- decoder embedding ----
    const int rowsD = 16 * 256;
    embed_k<<<cdiv(rowsD * 512, 256), 256, 0, stream>>>(
        x_dec, dec_vw, dec_vb, x_mark_dec, dec_mw, dec_mb, Yd, rowsD, 7, 4, FLAG);

    // ---- decoder (all GEMMs via 64x64 for concurrency) ----
    bf16* CQ  = QKV;                       // [4096][512]
    bf16* CKV = QKV + (size_t)4096 * 512;  // [2080][1024]
    for (int i = 0; i < 2; ++i) {
        const unsigned b0 = (unsigned)i * 4u * 512u;
        // self-attention
        gemm64(Yd, DSWt + (size_t)i * 4 * 262144, dsb, b0, QKV, rowsD, 1536, 512, 512, 1536, false);
        fattn_k<1><<<dim3(16, 8, 16), 512, 0, stream>>>(
            QKV, QKV + 512, QKV + 1024, 1536, 1536, 256, 256);
        gemm64(QKV, DSWt + (size_t)(i * 4 + 3) * 262144, dsb, b0 + 1536u, OUT, rowsD, 512, 512, 1536, 512, false);
        ln_off_k<<<rowsD, 256, 0, stream>>>(Yd, OUT, dln, (unsigned)(i * 3 + 0) * 1024u, Yd, FLAG);

        // cross-attention
        gemm64(Yd, DCWt + (size_t)i * 4 * 262144, dcb, b0, CQ, rowsD, 512, 512, 512, 512, false);
        gemm64(MEMb, DCWt + (size_t)(i * 4 + 1) * 262144, dcb, b0 + 512u, CKV, 16 * Lm, 1024, 512, 512, 1024, false);
        fattn_k<2><<<dim3(16, 8, 16), 512, 0, stream>>>(
            CQ, CKV, CKV + 512, 512, 1024, 256, Lm);
        gemm64(CQ, DCWt + (size_t)(i * 4 + 3) * 262144, dcb, b0 + 1536u, OUT, rowsD, 512, 512, 512, 512, false);
        ln_off_k<<<rowsD, 256, 0, stream>>>(Yd, OUT, dln, (unsigned)(i * 3 + 1) * 1024u, Yd, FLAG);

        // FFN
        gemm64(Yd, DW1T + (size_t)i * 1048576, dffb1, (unsigned)i * 2048u, HID, rowsD, 2048, 512, 512, 2048, true);
        gemm64(HID, DW2T + (size_t)i * 1048576, dffb2, (unsigned)i * 512u, OUT, rowsD, 512, 2048, 2048, 512, false);
        ln_off_k<<<rowsD, 256, 0, stream>>>(Yd, OUT, dln, (unsigned)(i * 3 + 2) * 1024u, Yd, FLAG);
    }

    ln_off_k<<<rowsD, 256, 0, stream>>>(Yd, nullptr, dec_norm, 0u, OUT, FLAG);
    fc_k<<<cdiv(rowsD * 7, 256), 256, 0, stream>>>(OUT, fcw, fcb, d_out, rowsD * 7, FLAG);
}

// Round 6
// 1443.441 us; speedup vs baseline: 1.3258x; 1.0722x over previous
//
#include <hip/hip_runtime.h>
#include <hip/hip_bf16.h>

// Informer forward, MI355X. Round 14: fattn serial-chain fusion (latency exposure).
//  - Round-13 counters: fattn<0> 96.6us, VALUBusy 32, Occ 44, HBM 4.4% -> latency-bound;
//    VALU work alone ~31us => 3x stall gap from per-wave serial chains.
//  - MODE 0: the two per-row radix searches per wave now run INTERLEAVED in one trial
//    loop (TA/TB, shared early-exit). In-order wave issues row-B v_cmps while row-A's
//    SALU count resolves -> ~halves exposed chain latency. Compaction + PV of both
//    rows fused (32 independent V loads in flight). Selection set identical.
//  - MODE 1/2: PV fused across the wave's two rows: one 128B V-row load feeds both
//    rows' FMAs (masked cols are exactly 0 -> run to kmax unguarded, bit-identical),
//    unroll 8 -> 8 loads in flight (was ~1-2, 2B/lane serial walk, run twice).
//  - Q stage uses all 512 threads (was t<128; 6 waves idled at the first barrier).
// Retained: round-13 GEMM split (mgemm 128^2 for L1 QKV/FFN1, mgemm64 64^2 4-wave for
// the rest), ballot radix-select, direct-global K frags, global_load_lds staging,
// weight-transpose prologue, dtype sniffer.
// Round 13: passed, absmax 0.0117, 1547.7 us.
// B=16, LE=512, LD=256, D=512, H=8, dk=64, DFF=2048, NE=3, ND=2, TOPK=16.
// Encoder lengths: 512 -> conv(514)/pool -> 257 -> conv(259)/pool -> 130.

#define DM 512
#define DK 64

using bf16 = __hip_bfloat16;
typedef short s8v __attribute__((ext_vector_type(8)));
typedef float f4v __attribute__((ext_vector_type(4)));

__device__ inline float b2f(bf16 x) { return __bfloat162float(x); }
__device__ inline float u2f(unsigned short u) { return __uint_as_float((unsigned)u << 16); }

// flag f: 1 = raw inputs are bf16, 0 = raw inputs are fp32. idx in ELEMENTS.
__device__ inline float ldw(const void* p, unsigned i, int f) {
    return f ? b2f(((const bf16*)p)[i]) : ((const float*)p)[i];
}

// order-preserving float->u32 (monotonic)
__device__ inline unsigned f2ord(float s) {
    unsigned u = __float_as_uint(s);
    return u ^ ((unsigned)((int)u >> 31) | 0x80000000u);
}

// popcount of mask bits strictly below this lane
__device__ inline int popc_lt(unsigned long long m) {
    return (int)__builtin_amdgcn_mbcnt_hi((unsigned)(m >> 32),
            __builtin_amdgcn_mbcnt_lo((unsigned)m, 0u));
}

// async global->LDS, 16 B per lane; lds dst must be wave-uniform (lane i lands at dst+16*i)
__device__ inline void gl_lds16(const short* g, short* l) {
    __builtin_amdgcn_global_load_lds(
        (const __attribute__((address_space(1))) unsigned int*)g,
        (__attribute__((address_space(3))) unsigned int*)l,
        16, 0, 0);
}

// ---------------- dtype sniffer ----------------
__global__ __launch_bounds__(256) void sniff_k(const unsigned* __restrict__ x, int nwords,
                                               int* __restrict__ flag) {
    __shared__ int red[4];
    const int t = threadIdx.x;
    int c = 0;
    for (int i = t; i < nwords; i += 256) c += ((x[i] & 0x7F80u) == 0x3F80u) ? 1 : 0;
    #pragma unroll
    for (int o = 32; o > 0; o >>= 1) c += __shfl_down(c, o);
    __syncthreads();
    if ((t & 63) == 0) red[t >> 6] = c;
    __syncthreads();
    if (t == 0) flag[0] = (red[0] + red[1] + red[2] + red[3] > nwords / 20) ? 1 : 0;
}

// ---------------- reductions (blockDim == 256) ----------------
__device__ inline float block_sum256(float v, float* red) {
    #pragma unroll
    for (int o = 32; o > 0; o >>= 1) v += __shfl_down(v, o);
    __syncthreads();
    if ((threadIdx.x & 63) == 0) red[threadIdx.x >> 6] = v;
    __syncthreads();
    return red[0] + red[1] + red[2] + red[3];
}

// ---------------- embedding ----------------
__global__ __launch_bounds__(256) void embed_k(
    const void* __restrict__ xv, const void* __restrict__ vw, const void* __restrict__ vb,
    const void* __restrict__ xm, const void* __restrict__ mw, const void* __restrict__ mb,
    bf16* __restrict__ Out, int rows, int Cv, int Cm, const int* __restrict__ flagp)
{
    const int f = *flagp;
    int i = blockIdx.x * 256 + threadIdx.x;
    if (i >= rows * DM) return;
    const int r = i >> 9, d = i & 511;
    float acc = ldw(vb, d, f) + ldw(mb, d, f);
    for (int c = 0; c < Cv; ++c) acc += ldw(xv, r * Cv + c, f) * ldw(vw, c * DM + d, f);
    for (int c = 0; c < Cm; ++c) acc += ldw(xm, r * Cm + c, f) * ldw(mw, c * DM + d, f);
    Out[i] = __float2bfloat16(acc);
}

// ---------------- weight transpose: raw [K][N] -> bf16 [N][K]; z batches sub-mats ----------------
__global__ __launch_bounds__(256) void transp_k(
    const void* __restrict__ W, unsigned off, unsigned zstride, bf16* __restrict__ out,
    int K, int N, const int* __restrict__ flagp)
{
    __shared__ float tile[32][33];
    const int f = *flagp;
    const unsigned zo = blockIdx.z * zstride;
    const int t = threadIdx.x;
    const int tx = t & 31, ty = t >> 5;               // 32 x 8
    const int n0 = blockIdx.x * 32, k0 = blockIdx.y * 32;
    #pragma unroll
    for (int i = 0; i < 4; ++i)
        tile[ty + 8 * i][tx] = ldw(W, off + zo + (unsigned)(k0 + ty + 8 * i) * N + n0 + tx, f);
    __syncthreads();
    #pragma unroll
    for (int i = 0; i < 4; ++i)
        out[(size_t)zo + (size_t)(n0 + ty + 8 * i) * K + k0 + tx] = __float2bfloat16(tile[tx][ty + 8 * i]);
}

// ---------------- MFMA GEMM 128x128 (256 thr): C = A[M,K]@Wt[N,K]^T + bias ----------------
// Staging via global_load_lds (16 B/lane), unpadded [row][32]-short LDS tiles.
// Used only for large-grid GEMMs (encoder L1 QKV / FFN1: >= 768 blocks).
template<bool G3, bool RELU>
__global__ __launch_bounds__(256) void mgemm_k(
    const short* __restrict__ A, const int* __restrict__ ridx,
    const short* __restrict__ Wt,
    const void* __restrict__ bias, unsigned boff0,
    bf16* __restrict__ C, int M, int N, int K, int lda, int ldc,
    const int* __restrict__ flagp)
{
    __shared__ short As[128 * 32];
    __shared__ short Ws[128 * 32];
    const int t = threadIdx.x;
    const int bm = blockIdx.y * 128, bn = blockIdx.x * 128;
    const int lane = t & 63, wave = t >> 6;
    const int mbase = (wave >> 1) * 64, nbase = (wave & 1) * 64;
    const int l15 = lane & 15, quad = lane >> 4;
    const int lrow = lane >> 2, lk = (lane & 3) * 8;

    f4v acc[4][4] = {};

    for (int k0 = 0; k0 < K; k0 += 32) {
        __syncthreads();
        #pragma unroll
        for (int j = 0; j < 2; ++j) {
            const int rb = wave * 32 + j * 16;
            const int row = bm + rb + lrow;
            const int rowc = row < M ? row : M - 1;
            const short* g;
            if (G3) {
                const int r = ridx[(k0 >> 9) * M + rowc];
                g = A + (size_t)r * lda + (k0 & 511) + lk;
            } else {
                g = A + (size_t)rowc * lda + k0 + lk;
            }
            gl_lds16(g, &As[rb * 32]);
        }
        #pragma unroll
        for (int j = 0; j < 2; ++j) {
            const int nb = wave * 32 + j * 16;
            gl_lds16(Wt + (size_t)(bn + nb + lrow) * K + k0 + lk, &Ws[nb * 32]);
        }
        __syncthreads();
        s8v af[4], bfv[4];
        #pragma unroll
        for (int i = 0; i < 4; ++i) {
            af[i]  = *(const s8v*)&As[(mbase + i * 16 + l15) * 32 + quad * 8];
            bfv[i] = *(const s8v*)&Ws[(nbase + i * 16 + l15) * 32 + quad * 8];
        }
        #pragma unroll
        for (int mi = 0; mi < 4; ++mi)
            #pragma unroll
            for (int ni = 0; ni < 4; ++ni)
                acc[mi][ni] = __builtin_amdgcn_mfma_f32_16x16x32_bf16(
                    af[mi], bfv[ni], acc[mi][ni], 0, 0, 0);
    }

    const int f = *flagp;
    float bv[4];
    #pragma unroll
    for (int ni = 0; ni < 4; ++ni)
        bv[ni] = ldw(bias, boff0 + (unsigned)(bn + nbase + ni * 16 + l15), f);

    #pragma unroll
    for (int mi = 0; mi < 4; ++mi) {
        #pragma unroll
        for (int r = 0; r < 4; ++r) {
            const int row = bm + mbase + mi * 16 + quad * 4 + r;
            if (row < M) {
                #pragma unroll
                for (int ni = 0; ni < 4; ++ni) {
                    float o = acc[mi][ni][r] + bv[ni];
                    if (RELU) o = fmaxf(o, 0.f);
                    C[(size_t)row * ldc + bn + nbase + ni * 16 + l15] = __float2bfloat16(o);
                }
            }
        }
    }
}

// ---------------- MFMA GEMM 64x64 (256 thr, 4 waves x 32x32): concurrency-first ----------------
// grid (N/64, cdiv(M,64)): >= 4 blocks/CU (8 KB LDS), 16 waves/CU.
template<bool G3, bool RELU>
__global__ __launch_bounds__(256) void mgemm64_k(
    const short* __restrict__ A, const int* __restrict__ ridx,
    const short* __restrict__ Wt,
    const void* __restrict__ bias, unsigned boff0,
    bf16* __restrict__ C, int M, int N, int K, int lda, int ldc,
    const int* __restrict__ flagp)
{
    __shared__ short As[64 * 32];
    __shared__ short Ws[64 * 32];
    const int t = threadIdx.x;
    const int bm = blockIdx.y * 64, bn = blockIdx.x * 64;
    const int lane = t & 63, wave = t >> 6;
    const int mbase = (wave >> 1) * 32, nbase = (wave & 1) * 32;
    const int l15 = lane & 15, quad = lane >> 4;
    const int lrow = lane >> 2, lk = (lane & 3) * 8;

    f4v acc[2][2] = {};

    for (int k0 = 0; k0 < K; k0 += 32) {
        __syncthreads();
        {   // A chunk: 16 rows per wave (4 waves cover 64)
            const int rb = wave * 16;
            const int row = bm + rb + lrow;
            const int rowc = row < M ? row : M - 1;
            const short* g;
            if (G3) {
                const int r = ridx[(k0 >> 9) * M + rowc];
                g = A + (size_t)r * lda + (k0 & 511) + lk;
            } else {
                g = A + (size_t)rowc * lda + k0 + lk;
            }
            gl_lds16(g, &As[rb * 32]);
        }
        {   // B chunk: 16 rows per wave
            const int nb = wave * 16;
            gl_lds16(Wt + (size_t)(bn + nb + lrow) * K + k0 + lk, &Ws[nb * 32]);
        }
        __syncthreads();
        s8v af[2], bfv[2];
        #pragma unroll
        for (int i = 0; i < 2; ++i) {
            af[i]  = *(const s8v*)&As[(mbase + i * 16 + l15) * 32 + quad * 8];
            bfv[i] = *(const s8v*)&Ws[(nbase + i * 16 + l15) * 32 + quad * 8];
        }
        #pragma unroll
        for (int mi = 0; mi < 2; ++mi)
            #pragma unroll
            for (int ni = 0; ni < 2; ++ni)
                acc[mi][ni] = __builtin_amdgcn_mfma_f32_16x16x32_bf16(
                    af[mi], bfv[ni], acc[mi][ni], 0, 0, 0);
    }

    const int f = *flagp;
    float bv[2];
    #pragma unroll
    for (int ni = 0; ni < 2; ++ni)
        bv[ni] = ldw(bias, boff0 + (unsigned)(bn + nbase + ni * 16 + l15), f);

    #pragma unroll
    for (int mi = 0; mi < 2; ++mi) {
        #pragma unroll
        for (int r = 0; r < 4; ++r) {
            const int row = bm + mbase + mi * 16 + quad * 4 + r;
            if (row < M) {
                #pragma unroll
                for (int ni = 0; ni < 2; ++ni) {
                    float o = acc[mi][ni][r] + bv[ni];
                    if (RELU) o = fmaxf(o, 0.f);
                    C[(size_t)row * ldc + bn + nbase + ni * 16 + l15] = __float2bfloat16(o);
                }
            }
        }
    }
}

// ---------------- fused tile attention (strided q/k/v), 512 threads ----------------
// MODE 0: ProbSparse top-16. MODE 1: causal. MODE 2: plain cross.
// 8 waves: phase 1 = MFMA QK^T, direct-global K frags, 2-deep load pipeline;
// phase 2+3 = each wave owns rows {wave, wave+8}, processed FUSED (independent
// serial chains interleaved to hide VALU->SALU latency; shared V loads in MODE 1/2).
template<int MODE>
__global__ __launch_bounds__(512, 8) void fattn_k(
    bf16* __restrict__ q, const bf16* __restrict__ k, const bf16* __restrict__ v,
    int ldq, int ldkv, int Lq, int Lk)
{
    __shared__ short Qs[16 * 72];
    __shared__ float S[16 * 516];
    __shared__ int   PC[16][16];
    __shared__ float PE[16][16];

    const int t = threadIdx.x;
    const int q0 = blockIdx.x * 16, h = blockIdx.y, b = blockIdx.z;
    const int lane = t & 63, wave = t >> 6;           // 8 waves
    const int l15 = lane & 15, quad = lane >> 4;

    const int qv = (Lq - q0) < 16 ? (Lq - q0) : 16;

    const bf16* Kbase = k + (size_t)b * Lk * ldkv + h * DK;
    const bf16* Vbase = v + (size_t)b * Lk * ldkv + h * DK;
    bf16* Qbase = q + (size_t)(b * Lq + q0) * ldq + h * DK;

    const int kmax = (MODE == 1) ? (q0 + 16 < Lk ? q0 + 16 : Lk) : Lk;
    const int ntile = (kmax + 63) >> 6;
    const int kpad = ntile << 6;
    const int nchunk = kpad >> 4;

    {   // Q stage: all 512 threads (4B each; 16 rows x 128B)
        const int qr = t >> 5;
        const int qsrc = qr < qv ? qr : qv - 1;
        *(ushort2*)&Qs[qr * 72 + (t & 31) * 2] =
            *(const ushort2*)(Qbase + (size_t)qsrc * ldq + (t & 31) * 2);
    }
    __syncthreads();

    // ---- phase 1: S = QK^T / 8 (+ masks); 2-deep K-load pipeline ----
    {
        const s8v a0 = *(const s8v*)&Qs[l15 * 72 + quad * 8];
        const s8v a1 = *(const s8v*)&Qs[l15 * 72 + 32 + quad * 8];
        int c = wave;
        s8v b0, b1;
        if (c < nchunk) {
            int srow = c * 16 + l15; if (srow >= Lk) srow = Lk - 1;
            const bf16* kp = Kbase + (size_t)srow * ldkv + quad * 8;
            b0 = *(const s8v*)kp;
            b1 = *(const s8v*)(kp + 32);
        }
        while (c < nchunk) {
            const int cn = c + 8;
            s8v n0, n1;
            if (cn < nchunk) {
                int srow = cn * 16 + l15; if (srow >= Lk) srow = Lk - 1;
                const bf16* kp = Kbase + (size_t)srow * ldkv + quad * 8;
                n0 = *(const s8v*)kp;
                n1 = *(const s8v*)(kp + 32);
            }
            f4v acc = {0.f, 0.f, 0.f, 0.f};
            acc = __builtin_amdgcn_mfma_f32_16x16x32_bf16(a0, b0, acc, 0, 0, 0);
            acc = __builtin_amdgcn_mfma_f32_16x16x32_bf16(a1, b1, acc, 0, 0, 0);
            const int colg = c * 16 + l15;
            #pragma unroll
            for (int r = 0; r < 4; ++r) {
                const int qrow = quad * 4 + r;
                float s = acc[r] * 0.125f;
                if (colg >= Lk) s = -1e9f;
                if (MODE == 1 && colg > q0 + qrow) s = -1e9f;
                S[qrow * 516 + colg] = s;
            }
            b0 = n0; b1 = n1; c = cn;
        }
    }
    __syncthreads();

    // ---- phase 2+3: rows {wave, wave+8} processed fused ----
    const int rowA = wave, rowB = wave + 8;
    float aA = 0.f, aB = 0.f;
    float invA, invB;
    if (MODE == 0) {
        // packed keys: 23-bit quantized score | 9-bit col; 0 for padded cols
        unsigned keyA[8], keyB[8];
        #pragma unroll
        for (int j = 0; j < 8; ++j) {
            const int col = lane + 64 * j;
            const bool ok = col < kpad;
            keyA[j] = ok ? ((f2ord(S[rowA * 516 + col]) & 0xFFFFFE00u) | (unsigned)col) : 0u;
            keyB[j] = ok ? ((f2ord(S[rowB * 516 + col]) & 0xFFFFFE00u) | (unsigned)col) : 0u;
        }
        // row maxes (exp offsets): two interleaved butterflies
        unsigned kmA = keyA[0], kmB = keyB[0];
        #pragma unroll
        for (int j = 1; j < 8; ++j) {
            kmA = kmA > keyA[j] ? kmA : keyA[j];
            kmB = kmB > keyB[j] ? kmB : keyB[j];
        }
        #pragma unroll
        for (int off = 1; off < 64; off <<= 1) {
            const unsigned oA = __shfl_xor(kmA, off);
            const unsigned oB = __shfl_xor(kmB, off);
            kmA = kmA > oA ? kmA : oA;
            kmB = kmB > oB ? kmB : oB;
        }
        const float mrA = S[rowA * 516 + (int)(kmA & 511u)];
        const float mrB = S[rowB * 516 + (int)(kmB & 511u)];

        // interleaved full-32-bit binary searches (independent chains hide each
        // other's VALU->SALU->branch latency). Same selection as the sequential
        // version: largest T with count(key >= T) >= 16; keys distinct -> exact 16.
        unsigned TA = 0u, TB = 0u;
        bool dA = false, dB = false;
        for (int bbit = 31; bbit >= 0; --bbit) {
            if (!dA) {
                const unsigned T2 = TA | (1u << bbit);
                int c = 0;
                #pragma unroll
                for (int j = 0; j < 8; ++j)
                    c += (int)__popcll(__ballot(keyA[j] >= T2));
                if (c >= 16) { TA = T2; dA = (c == 16); }
            }
            if (!dB) {
                const unsigned T2 = TB | (1u << bbit);
                int c = 0;
                #pragma unroll
                for (int j = 0; j < 8; ++j)
                    c += (int)__popcll(__ballot(keyB[j] >= T2));
                if (c >= 16) { TB = T2; dB = (c == 16); }
            }
            if (dA && dB) break;
        }

        // compaction: exactly the 16 keys >= T per row -> (col, e) in LDS
        int cntA = 0, cntB = 0;
        #pragma unroll
        for (int j = 0; j < 8; ++j) {
            const bool sA = keyA[j] >= TA;
            const unsigned long long balA = __ballot(sA);
            if (sA) {
                const int p = cntA + popc_lt(balA);
                const int col = (int)(keyA[j] & 511u);
                PC[rowA][p] = col;
                PE[rowA][p] = expf(S[rowA * 516 + col] - mrA);
            }
            cntA += (int)__popcll(balA);
            const bool sB = keyB[j] >= TB;
            const unsigned long long balB = __ballot(sB);
            if (sB) {
                const int p = cntB + popc_lt(balB);
                const int col = (int)(keyB[j] & 511u);
                PC[rowB][p] = col;
                PE[rowB][p] = expf(S[rowB * 516 + col] - mrB);
            }
            cntB += (int)__popcll(balB);
        }
        // wave-private rows: same-wave DS ops in order; no barrier needed

        float denA = 0.f, denB = 0.f;
        #pragma unroll
        for (int it = 0; it < 16; ++it) {
            const int cA = PC[rowA][it];
            const float eA = PE[rowA][it];
            denA += eA;
            aA += eA * b2f(Vbase[(size_t)cA * ldkv + lane]);
            const int cB = PC[rowB][it];
            const float eB = PE[rowB][it];
            denB += eB;
            aB += eB * b2f(Vbase[(size_t)cB * ldkv + lane]);
        }
        invA = 1.f / denA;
        invB = 1.f / denB;
    } else {
        float lvA = -INFINITY, lvB = -INFINITY;
        #pragma unroll
        for (int j = 0; j < 8; ++j) {
            const int col = lane + 64 * j;
            if (col < kpad) {
                lvA = fmaxf(lvA, S[rowA * 516 + col]);
                lvB = fmaxf(lvB, S[rowB * 516 + col]);
            }
        }
        #pragma unroll
        for (int off = 1; off < 64; off <<= 1) {
            lvA = fmaxf(lvA, __shfl_xor(lvA, off));
            lvB = fmaxf(lvB, __shfl_xor(lvB, off));
        }
        float pA = 0.f, pB = 0.f;
        #pragma unroll
        for (int j = 0; j < 8; ++j) {
            const int col = lane + 64 * j;
            if (col < kpad) {
                const float wA = expf(S[rowA * 516 + col] - lvA);
                const float wB = expf(S[rowB * 516 + col] - lvB);
                S[rowA * 516 + col] = wA;
                S[rowB * 516 + col] = wB;
                pA += wA; pB += wB;
            }
        }
        #pragma unroll
        for (int off = 1; off < 64; off <<= 1) {
            pA += __shfl_xor(pA, off);
            pB += __shfl_xor(pB, off);
        }
        invA = 1.f / pA;
        invB = 1.f / pB;
        // fused PV: one V row feeds both rows' FMAs. Causal-masked cols have
        // w = exp(-1e9 - lv) = +0 exactly -> running to kmax is bit-identical.
        #pragma unroll 8
        for (int k2 = 0; k2 < kmax; ++k2) {
            const float vv = b2f(Vbase[(size_t)k2 * ldkv + lane]);
            aA += S[rowA * 516 + k2] * vv;
            aB += S[rowB * 516 + k2] * vv;
        }
    }
    if (rowA < qv)
        Qbase[(size_t)rowA * ldq + lane] = __float2bfloat16(aA * invA);
    if (rowB < qv)
        Qbase[(size_t)rowB * ldq + lane] = __float2bfloat16(aB * invB);
}

// ---------------- layernorm over D=512, optional residual; in-place safe ----------------
__global__ __launch_bounds__(256) void ln_off_k(
    const bf16* __restrict__ X, const bf16* __restrict__ R,
    const void* __restrict__ gb, unsigned goff,
    bf16* __restrict__ Out, const int* __restrict__ flagp)
{
    __shared__ float red[4];
    const int f = *flagp;
    const int t = threadIdx.x;
    const size_t base = (size_t)blockIdx.x * DM;
    float v0 = b2f(X[base + t]), v1 = b2f(X[base + t + 256]);
    if (R) { v0 += b2f(R[base + t]); v1 += b2f(R[base + t + 256]); }
    const float mean = block_sum256(v0 + v1, red) * (1.f / 512.f);
    const float d0 = v0 - mean, d1 = v1 - mean;
    const float var = block_sum256(d0 * d0 + d1 * d1, red) * (1.f / 512.f);
    const float rstd = rsqrtf(var + 1e-5f);
    Out[base + t]       = __float2bfloat16(d0 * rstd * ldw(gb, goff + t, f)       + ldw(gb, goff + 512 + t, f));
    Out[base + t + 256] = __float2bfloat16(d1 * rstd * ldw(gb, goff + t + 256, f) + ldw(gb, goff + 768 + t, f));
}

// ---------------- conv distill helpers ----------------
// conv weights w[2][o][c][j] -> transposed GEMM layout wt[layer][o][j*512+c]
__global__ __launch_bounds__(256) void convw_k(const void* __restrict__ w,
                                               bf16* __restrict__ wt, int total,
                                               const int* __restrict__ flagp) {
    const int f = *flagp;
    int i = blockIdx.x * 256 + threadIdx.x;
    if (i >= total) return;
    const int layer = i / 786432, rem2 = i % 786432;
    const int o = rem2 / 1536, rem = rem2 % 1536;
    const int j = rem >> 9, c = rem & 511;
    wt[i] = __float2bfloat16(ldw(w, (unsigned)layer * 786432u + (unsigned)(o * 512 + c) * 3 + j, f));
}

__global__ __launch_bounds__(256) void convidx_k(int* __restrict__ idx, int Lc, int L, int total) {
    int i = blockIdx.x * 256 + threadIdx.x;
    if (i >= total) return;
    const int j = i / (16 * Lc), mrem = i % (16 * Lc);
    const int b = mrem / Lc, l = mrem % Lc;
    int src = l + j - 2;
    src %= L; if (src < 0) src += L;
    idx[i] = b * L + src;
}

__global__ __launch_bounds__(256) void bnstat1_k(const bf16* __restrict__ Y, float* __restrict__ part, int M) {
    const int t = threadIdx.x;
    float s0 = 0.f, q0 = 0.f, s1 = 0.f, q1 = 0.f;
    for (int r = blockIdx.x; r < M; r += gridDim.x) {
        const ushort2 u = *reinterpret_cast<const ushort2*>(Y + (size_t)r * DM + t * 2);
        const float a = u2f(u.x), c = u2f(u.y);
        s0 += a; q0 += a * a;
        s1 += c; q1 += c * c;
    }
    float* p = part + (size_t)blockIdx.x * 1024;
    p[2 * t] = s0; p[2 * t + 1] = s1;
    p[512 + 2 * t] = q0; p[512 + 2 * t + 1] = q1;
}

__global__ __launch_bounds__(256) void bnstat2_k(const float* __restrict__ part, float* __restrict__ stats,
                                                 int nchunk, int M) {
    const int ch = blockIdx.x * 256 + threadIdx.x;
    if (ch >= 512) return;
    float S = 0.f, Qs = 0.f;
    for (int c = 0; c < nchunk; ++c) { S += part[c * 1024 + ch]; Qs += part[c * 1024 + 512 + ch]; }
    const float mean = S / (float)M;
    const float var = Qs / (float)M - mean * mean;
    stats[ch] = mean;
    stats[512 + ch] = fmaxf(var, 0.f);
}

__global__ __launch_bounds__(256) void bnpool_k(
    const bf16* __restrict__ Yc, const float* __restrict__ stats,
    const void* __restrict__ g, const void* __restrict__ bb, unsigned off,
    bf16* __restrict__ Out, int Lc, int Lout, int total, const int* __restrict__ flagp)
{
    const int f = *flagp;
    int i = blockIdx.x * 256 + threadIdx.x;
    if (i >= total) return;
    const int ch = i & 511;
    const int lp = (i >> 9) % Lout;
    const int b = i / (512 * Lout);
    const float mean = stats[ch], var = stats[512 + ch];
    const float sc = ldw(g, off + ch, f) * rsqrtf(var + 1e-5f);
    const float sh = ldw(bb, off + ch, f) - mean * sc;
    float mx = -INFINITY;
    const int l0 = 2 * lp - 1;
    #pragma unroll
    for (int d = 0; d < 3; ++d) {
        const int l = l0 + d;
        if (l >= 0 && l < Lc) {
            float v = b2f(Yc[((size_t)b * Lc + l) * DM + ch]) * sc + sh;
            v = v > 0.f ? v : expm1f(v);  // ELU
            mx = fmaxf(mx, v);
        }
    }
    Out[((size_t)b * Lout + lp) * DM + ch] = __float2bfloat16(mx);
}

// ---------------- final projection to CO=7, dtype-matched store ----------------
__global__ __launch_bounds__(256) void fc_k(
    const bf16* __restrict__ Yn, const void* __restrict__ fcw, const void* __restrict__ fcb,
    void* __restrict__ out, int total, const int* __restrict__ flagp)
{
    const int f = *flagp;
    int i = blockIdx.x * 256 + threadIdx.x;
    if (i >= total) return;
    const int r = i / 7, co = i % 7;
    const bf16* yr = Yn + (size_t)r * DM;
    float acc = ldw(fcb, co, f);
    for (int d = 0; d < DM; ++d) acc += b2f(yr[d]) * ldw(fcw, d * 7 + co, f);
    if (f) ((bf16*)out)[i] = __float2bfloat16(acc);
    else   ((float*)out)[i] = acc;
}

// =============================================================================
extern "C" void kernel_launch(void* const* d_in, const int* in_sizes, int n_in,
                              void* d_out, int out_size, void* d_ws, size_t ws_size,
                              hipStream_t stream)
{
    const void* x_enc      = d_in[0];
    const void* x_mark_enc = d_in[1];
    const void* x_dec      = d_in[2];
    const void* x_mark_dec = d_in[3];
    const void* enc_vw = d_in[4];
    const void* enc_vb = d_in[5];
    const void* enc_mw = d_in[6];
    const void* enc_mb = d_in[7];
    const void* dec_vw = d_in[8];
    const void* dec_vb = d_in[9];
    const void* dec_mw = d_in[10];
    const void* dec_mb = d_in[11];
    const void* eW    = d_in[12];
    const void* ebi   = d_in[13];
    const void* effw1 = d_in[14];
    const void* effb1 = d_in[15];
    const void* effw2 = d_in[16];
    const void* effb2 = d_in[17];
    const void* eln1  = d_in[18];
    const void* eln2  = d_in[19];
    const void* cw    = d_in[20];
    const void* cb    = d_in[21];
    const void* cbn_g = d_in[22];
    const void* cbn_b = d_in[23];
    const void* enc_norm = d_in[24];
    const void* dsW   = d_in[25];
    const void* dsb   = d_in[26];
    const void* dcW   = d_in[27];
    const void* dcb   = d_in[28];
    const void* dffw1 = d_in[29];
    const void* dffb1 = d_in[30];
    const void* dffw2 = d_in[31];
    const void* dffb2 = d_in[32];
    const void* dln   = d_in[33];
    const void* dec_norm = d_in[34];
    const void* fcw   = d_in[35];
    const void* fcb   = d_in[36];

    // ---- workspace layout (~90 MiB; 111 MiB footprint ran clean in round 1) ----
    // X    [0, 8M)      : encoder acts; MEM + Yd in decoder phase
    // QKV  [8M, 40M)    : fused QKV / FFN hidden (aliased) / conv out / cross CQ+CKV
    // OUT  [40M, 48M)   : O-proj / FFN2 dest
    // WT   [48M, ~86.8M): ALL transposed weights (one-time prologue)
    // misc [88M, ~90M)  : IDX0/IDX1, PART, STATS, FLAG
    char* wsp = (char*)d_ws;
    bf16* X    = (bf16*)wsp;
    bf16* QKV  = (bf16*)(wsp + ((size_t)8 << 20));
    bf16* HID  = QKV;                                 // FFN hidden aliases dead QKV
    bf16* OUT  = (bf16*)(wsp + ((size_t)40 << 20));
    bf16* WT   = (bf16*)(wsp + ((size_t)48 << 20));
    int*   IDX0 = (int*)(wsp + ((size_t)88 << 20));   // 3*16*514 = 24672 ints
    int*   IDX1 = IDX0 + 24672;                       // 3*16*259 = 12432 ints
    float* PART = (float*)(wsp + ((size_t)89 << 20));
    float* STATS= (float*)(wsp + ((size_t)89 << 20) + (1 << 18));
    int*   FLAG = (int*)(wsp + ((size_t)89 << 20) + (1 << 18) + 4096);
    bf16* MEMb = X;                                               // [2080][512]
    bf16* Yd   = (bf16*)(wsp + (size_t)16 * 130 * 512 * 2);       // [4096][512]

    // transposed weight sub-arenas (element offsets)
    bf16* WTE  = WT;                    // enc QKVO: (i*4+q)*262144
    bf16* EW1T = WT + 3145728;          // + i*1048576
    bf16* EW2T = WT + 6291456;          // + i*1048576
    bf16* CWT  = WT + 9437184;          // + i*786432
    bf16* DSWt = WT + 11010048;         // + (i*4+q)*262144
    bf16* DCWt = WT + 13107200;
    bf16* DW1T = WT + 15204352;
    bf16* DW2T = WT + 17301504;

    auto cdiv = [](int a, int b) { return (a + b - 1) / b; };
    auto gemm = [&](const bf16* A, const bf16* Wt, const void* bias, unsigned boff,
                    bf16* C, int M, int N, int K, int lda, int ldc, bool relu) {
        dim3 g(N / 128, cdiv(M, 128));
        if (relu) mgemm_k<false, true><<<g, 256, 0, stream>>>(
            (const short*)A, nullptr, (const short*)Wt, bias, boff, C, M, N, K, lda, ldc, FLAG);
        else      mgemm_k<false, false><<<g, 256, 0, stream>>>(
            (const short*)A, nullptr, (const short*)Wt, bias, boff, C, M, N, K, lda, ldc, FLAG);
    };
    auto gemm64 = [&](const bf16* A, const bf16* Wt, const void* bias, unsigned boff,
                      bf16* C, int M, int N, int K, int lda, int ldc, bool relu) {
        dim3 g(N / 64, cdiv(M, 64));
        if (relu) mgemm64_k<false, true><<<g, 256, 0, stream>>>(
            (const short*)A, nullptr, (const short*)Wt, bias, boff, C, M, N, K, lda, ldc, FLAG);
        else      mgemm64_k<false, false><<<g, 256, 0, stream>>>(
            (const short*)A, nullptr, (const short*)Wt, bias, boff, C, M, N, K, lda, ldc, FLAG);
    };
    auto transp = [&](const void* W, unsigned zstride, int nz, bf16* out, int K, int N) {
        transp_k<<<dim3(N / 32, K / 32, nz), 256, 0, stream>>>(W, 0u, zstride, out, K, N, FLAG);
    };

    // ---- prologue: sniff, all weight transposes, conv indices, embeddings ----
    sniff_k<<<1, 256, 0, stream>>>((const unsigned*)x_mark_enc, 16384, FLAG);
    transp(eW,    262144u, 12, WTE,  512, 512);
    transp(effw1, 1048576u, 3, EW1T, 512, 2048);
    transp(effw2, 1048576u, 3, EW2T, 2048, 512);
    convw_k<<<cdiv(1572864, 256), 256, 0, stream>>>(cw, CWT, 1572864, FLAG);
    transp(dsW,   262144u, 8, DSWt, 512, 512);
    transp(dcW,   262144u, 8, DCWt, 512, 512);
    transp(dffw1, 1048576u, 2, DW1T, 512, 2048);
    transp(dffw2, 1048576u, 2, DW2T, 2048, 512);
    convidx_k<<<cdiv(24672, 256), 256, 0, stream>>>(IDX0, 514, 512, 24672);
    convidx_k<<<cdiv(12432, 256), 256, 0, stream>>>(IDX1, 259, 257, 12432);
    embed_k<<<cdiv(16 * 512 * 512, 256), 256, 0, stream>>>(
        x_enc, enc_vw, enc_vb, x_mark_enc, enc_mw, enc_mb, X, 16 * 512, 7, 4, FLAG);

    // ---- encoder ----
    int L = 512;
    for (int i = 0; i < 3; ++i) {
        const int rows = 16 * L;
        const unsigned b0 = (unsigned)i * 4u * 512u;
        // QKV: big grid only at L=512 -> mgemm; else 64x64 for concurrency
        if (i == 0) gemm(X, WTE + (size_t)i * 4 * 262144, ebi, b0, QKV, rows, 1536, 512, 512, 1536, false);
        else      gemm64(X, WTE + (size_t)i * 4 * 262144, ebi, b0, QKV, rows, 1536, 512, 512, 1536, false);
        fattn_k<0><<<dim3(cdiv(L, 16), 8, 16), 512, 0, stream>>>(
            QKV, QKV + 512, QKV + 1024, 1536, 1536, L, L);
        gemm64(QKV, WTE + (size_t)(i * 4 + 3) * 262144, ebi, b0 + 1536u, OUT, rows, 512, 512, 1536, 512, false);
        ln_off_k<<<rows, 256, 0, stream>>>(X, OUT, eln1, (unsigned)i * 1024u, X, FLAG);

        if (i == 0) gemm(X, EW1T + (size_t)i * 1048576, effb1, (unsigned)i * 2048u, HID, rows, 2048, 512, 512, 2048, true);
        else      gemm64(X, EW1T + (size_t)i * 1048576, effb1, (unsigned)i * 2048u, HID, rows, 2048, 512, 512, 2048, true);
        gemm64(HID, EW2T + (size_t)i * 1048576, effb2, (unsigned)i * 512u, OUT, rows, 512, 2048, 2048, 512, false);
        ln_off_k<<<rows, 256, 0, stream>>>(X, OUT, eln2, (unsigned)i * 1024u, X, FLAG);

        if (i < 2) {
            const int Lc = L + 2, Mc = 16 * Lc;
            const int* IDXi = (i == 0) ? IDX0 : IDX1;
            mgemm64_k<true, false><<<dim3(8, cdiv(Mc, 64)), 256, 0, stream>>>(
                (const short*)X, IDXi, (const short*)(CWT + (size_t)i * 786432),
                cb, (unsigned)i * 512u, QKV, Mc, 512, 1536, 512, 512, FLAG);
            bnstat1_k<<<32, 256, 0, stream>>>(QKV, PART, Mc);
            bnstat2_k<<<2, 256, 0, stream>>>(PART, STATS, 32, Mc);
            const int Lout = (L + 1) / 2 + 1;   // 514->257, 259->130
            const int tot = 16 * Lout * 512;
            bnpool_k<<<cdiv(tot, 256), 256, 0, stream>>>(
                QKV, STATS, cbn_g, cbn_b, (unsigned)i * 512u, X, Lc, Lout, tot, FLAG);
            L = Lout;
        }
    }
    const int Lm = L;  // 130
    ln_off_k<<<16 * Lm, 256, 0, stream>>>(X, nullptr, enc_norm, 0u, MEMb, FLAG);

    // ---- decoder embedding ----
    const int rowsD = 16 * 256;
    embed_k<<<cdiv(rowsD * 512, 256), 256, 0, stream>>>(
        x_dec, dec_vw, dec_vb, x_mark_dec, dec_mw, dec_mb, Yd, rowsD, 7, 4, FLAG);

    // ---- decoder (all GEMMs via 64x64 for concurrency) ----
    bf16* CQ  = QKV;                       // [4096][512]
    bf16* CKV = QKV + (size_t)4096 * 512;  // [2080][1024]
    for (int i = 0; i < 2; ++i) {
        const unsigned b0 = (unsigned)i * 4u * 512u;
        // self-attention
        gemm64(Yd, DSWt + (size_t)i * 4 * 262144, dsb, b0, QKV, rowsD, 1536, 512, 512, 1536, false);
        fattn_k<1><<<dim3(16, 8, 16), 512, 0, stream>>>(
            QKV, QKV + 512, QKV + 1024, 1536, 1536, 256, 256);
        gemm64(QKV, DSWt + (size_t)(i * 4 + 3) * 262144, dsb, b0 + 1536u, OUT, rowsD, 512, 512, 1536, 512, false);
        ln_off_k<<<rowsD, 256, 0, stream>>>(Yd, OUT, dln, (unsigned)(i * 3 + 0) * 1024u, Yd, FLAG);

        // cross-attention
        gemm64(Yd, DCWt + (size_t)i * 4 * 262144, dcb, b0, CQ, rowsD, 512, 512, 512, 512, false);
        gemm64(MEMb, DCWt + (size_t)(i * 4 + 1) * 262144, dcb, b0 + 512u, CKV, 16 * Lm, 1024, 512, 512, 1024, false);
        fattn_k<2><<<dim3(16, 8, 16), 512, 0, stream>>>(
            CQ, CKV, CKV + 512, 512, 1024, 256, Lm);
        gemm64(CQ, DCWt + (size_t)(i * 4 + 3) * 262144, dcb, b0 + 1536u, OUT, rowsD, 512, 512, 512, 512, false);
        ln_off_k<<<rowsD, 256, 0, stream>>>(Yd, OUT, dln, (unsigned)(i * 3 + 1) * 1024u, Yd, FLAG);

        // FFN
        gemm64(Yd, DW1T + (size_t)i * 1048576, dffb1, (unsigned)i * 2048u, HID, rowsD, 2048, 512, 512, 2048, true);
        gemm64(HID, DW2T + (size_t)i * 1048576, dffb2, (unsigned)i * 512u, OUT, rowsD, 512, 2048, 2048, 512, false);
        ln_off_k<<<rowsD, 256, 0, stream>>>(Yd, OUT, dln, (unsigned)(i * 3 + 2) * 1024u, Yd, FLAG);
    }

    ln_off_k<<<rowsD, 256, 0, stream>>>(Yd, nullptr, dec_norm, 0u, OUT, FLAG);
    fc_k<<<cdiv(rowsD * 7, 256), 256, 0, stream>>>(OUT, fcw, fcb, d_out, rowsD * 7, FLAG);
}